// Round 6
// baseline (4792.662 us; speedup 1.0000x reference)
//
#include <hip/hip_runtime.h>
#include <math.h>

// GPNN: B=8 graphs, N=128 nodes, DV=512, DE=256, K=3, C=117.
// R6: scan critical path = barrier -> GRU -> C -> corr -> B; phase-A bulk runs
// speculatively (stale G col i) inside the barrier-wait window, corrected after
// C(i). Own gi-partials kept in regs. plogit: 2-pass c-halves (2 blocks/CU),
// adj fused in. Three k_wh launches merged into one.

#define NB 8
#define NN 128
#define DVV 512
#define DEE 256
#define NCC 117
#define SB 16
#define PGOFF 196608   // floats per pg parity buffer (8*16*1536)

__device__ __forceinline__ float sigmf(float x) {
  x = fminf(fmaxf(x, -30.f), 30.f);
  return 1.0f / (1.0f + __expf(-x));
}
__device__ __forceinline__ float tanhf_fast(float x) {
  x = fminf(fmaxf(x, -15.f), 15.f);
  float e = __expf(2.0f * x);
  return (e - 1.0f) / (e + 1.0f);
}
__device__ __forceinline__ float sel8(const float4& a, const float4& b, int e) {
  switch (e) {
    case 0: return a.x; case 1: return a.y; case 2: return a.z; case 3: return a.w;
    case 4: return b.x; case 5: return b.y; case 6: return b.z; default: return b.w;
  }
}

// ---------------- h init ----------------
__global__ __launch_bounds__(256) void k_copy(const float* __restrict__ src, float* __restrict__ dst) {
  int i = blockIdx.x * 256 + threadIdx.x;
  ((float4*)dst)[i] = ((const float4*)src)[i];
}

// ---------------- ai/aj ----------------
__global__ __launch_bounds__(128) void k_av(const float* __restrict__ h, const float* __restrict__ w_link,
                                            float* __restrict__ av) {
  int b = blockIdx.x >> 7, n = blockIdx.x & 127;
  int lane = threadIdx.x & 63, half = threadIdx.x >> 6;
  const float* hc = h + (size_t)((b << 7) + n) * DVV;
  const float* w = w_link + half * DVV;
  float acc = 0.f;
#pragma unroll
  for (int t = 0; t < 8; ++t) { int d = lane + (t << 6); acc += w[d] * hc[d]; }
#pragma unroll
  for (int off = 32; off; off >>= 1) acc += __shfl_down(acc, off);
  if (lane == 0) av[(b << 8) + half * NN + n] = acc;
}

// ---------------- per-row: adj (fused) + P = W3 @ e_row (in place), 2 c-half passes ----------------
template <int FIRST>
__global__ __launch_bounds__(256) void k_plogit(const float* src, const float* __restrict__ w_msg,
                                                const float* __restrict__ w_link,
                                                const float* __restrict__ av,
                                                const float* __restrict__ b_link,
                                                float* e_buf, float* __restrict__ adj_out) {
  int b = blockIdx.x >> 7, i = blockIdx.x & 127;
  __shared__ __align__(16) float eL[128][132];   // one c-half, 67.6 KB -> 2 blocks/CU
  int tid = threadIdx.x;
  int cg = tid >> 3, sjb = tid & 7;
  int c0 = cg * 8, jb = sjb * 16;
  float accLE = 0.f;
  float acc[8][16];
#pragma unroll
  for (int r = 0; r < 8; ++r)
#pragma unroll
    for (int u = 0; u < 16; ++u) acc[r][u] = 0.f;

  for (int p = 0; p < 2; ++p) {
    if (p) __syncthreads();
    if (FIRST) {
      const float* s0 = src + (size_t)(b * NN + i) * NN * DEE + 128 * p;
      for (int l = tid * 4; l < 16384; l += 1024) {
        int j = l >> 7, c = l & 127;
        float4 v = *(const float4*)&s0[(size_t)j * DEE + c];
        eL[c + 0][j] = v.x; eL[c + 1][j] = v.y; eL[c + 2][j] = v.z; eL[c + 3][j] = v.w;
      }
    } else {
      const float* s0 = src + (size_t)(b * NN + i) * DEE * NN + (size_t)(128 * p) * NN;
      for (int l = tid * 4; l < 16384; l += 1024) {
        int c = l >> 7, j = l & 127;
        *(float4*)&eL[c][j] = *(const float4*)&s0[l];
      }
    }
    __syncthreads();
    if (tid < NN) {
      for (int c = 0; c < 128; ++c) accLE += w_link[1024 + 128 * p + c] * eL[c][tid];
    }
    for (int c = 0; c < 128; c += 4) {
      float4 w[8];
#pragma unroll
      for (int r = 0; r < 8; ++r)
        w[r] = *(const float4*)&w_msg[(size_t)(c0 + r) * 1280 + 1024 + 128 * p + c];
#pragma unroll
      for (int cc = 0; cc < 4; ++cc) {
        float4 e0 = *(const float4*)&eL[c + cc][jb];
        float4 e1 = *(const float4*)&eL[c + cc][jb + 4];
        float4 e2 = *(const float4*)&eL[c + cc][jb + 8];
        float4 e3 = *(const float4*)&eL[c + cc][jb + 12];
#pragma unroll
        for (int r = 0; r < 8; ++r) {
          float wv = ((const float*)&w[r])[cc];
          acc[r][0] += wv * e0.x;  acc[r][1] += wv * e0.y;  acc[r][2] += wv * e0.z;  acc[r][3] += wv * e0.w;
          acc[r][4] += wv * e1.x;  acc[r][5] += wv * e1.y;  acc[r][6] += wv * e1.z;  acc[r][7] += wv * e1.w;
          acc[r][8] += wv * e2.x;  acc[r][9] += wv * e2.y;  acc[r][10] += wv * e2.z; acc[r][11] += wv * e2.w;
          acc[r][12] += wv * e3.x; acc[r][13] += wv * e3.y; acc[r][14] += wv * e3.z; acc[r][15] += wv * e3.w;
        }
      }
    }
  }
  // P writes (in place)
#pragma unroll
  for (int r = 0; r < 8; ++r)
#pragma unroll
    for (int u4 = 0; u4 < 4; ++u4) {
      float4 o; o.x = acc[r][u4 * 4]; o.y = acc[r][u4 * 4 + 1]; o.z = acc[r][u4 * 4 + 2]; o.w = acc[r][u4 * 4 + 3];
      *(float4*)&e_buf[((size_t)(b * NN + i) * DEE + c0 + r) * NN + jb + u4 * 4] = o;
    }
  // adj row (fused)
  if (tid < NN) {
    float x = av[(b << 8) + NN + i] + av[(b << 8) + tid] + accLE + b_link[0];
    adj_out[((size_t)b * NN + i) * NN + tid] = sigmf(x);
  }
}

// ---------------- merged W@h kernel: GH (96 blk) + U (16) + G (16) ----------------
__global__ __launch_bounds__(256) void k_wh3(const float* __restrict__ w_hh, const float* __restrict__ w_msg,
                                             const float* __restrict__ b_hh, const float* __restrict__ b_msg,
                                             const float* __restrict__ h, float* __restrict__ GHo,
                                             float* __restrict__ Uo, float* __restrict__ Go) {
  int bx = blockIdx.x, b = blockIdx.y;
  const float* W; const float* bias; float* out; int ldw, R, r0;
  if (bx < 96)       { W = w_hh;        ldw = 512;  R = 1536; bias = b_hh;   out = GHo; r0 = bx * 16; }
  else if (bx < 112) { W = w_msg;       ldw = 1280; R = 256;  bias = b_msg;  out = Uo;  r0 = (bx - 96) * 16; }
  else               { W = w_msg + 512; ldw = 1280; R = 256;  bias = nullptr; out = Go; r0 = (bx - 112) * 16; }
  __shared__ float hT[128][129];
  __shared__ float wT[16][129];
  __shared__ float outT[16][129];
  int tid = threadIdx.x;
  int n = tid & 127, rr = tid >> 7;
  float acc8[8] = {0, 0, 0, 0, 0, 0, 0, 0};
  for (int dc = 0; dc < DVV; dc += 128) {
    if (dc) __syncthreads();
    for (int l = tid * 4; l < 16384; l += 1024) {
      int nn = l >> 7, d = l & 127;
      float4 v = *(const float4*)&h[((size_t)(b << 7) + nn) * DVV + dc + d];
      hT[d + 0][nn] = v.x; hT[d + 1][nn] = v.y; hT[d + 2][nn] = v.z; hT[d + 3][nn] = v.w;
    }
    for (int l = tid; l < 2048; l += 256) {
      int r = l >> 7, d = l & 127;
      wT[r][d] = W[(size_t)(r0 + r) * ldw + dc + d];
    }
    __syncthreads();
    for (int d = 0; d < 128; ++d) {
      float hval = hT[d][n];
#pragma unroll
      for (int r8 = 0; r8 < 8; ++r8) acc8[r8] += wT[rr * 8 + r8][d] * hval;
    }
  }
#pragma unroll
  for (int r8 = 0; r8 < 8; ++r8) {
    int r = rr * 8 + r8;
    outT[r][n] = acc8[r8] + (bias ? bias[r0 + r] : 0.0f);
  }
  __syncthreads();
  int n2 = tid >> 1, q = tid & 1;
  size_t base = ((size_t)(b << 7) + n2) * R + r0 + q * 8;
  float4 o0; o0.x = outT[q * 8 + 0][n2]; o0.y = outT[q * 8 + 1][n2]; o0.z = outT[q * 8 + 2][n2]; o0.w = outT[q * 8 + 3][n2];
  float4 o1; o1.x = outT[q * 8 + 4][n2]; o1.y = outT[q * 8 + 5][n2]; o1.z = outT[q * 8 + 6][n2]; o1.w = outT[q * 8 + 7][n2];
  *(float4*)&out[base] = o0;
  *(float4*)&out[base + 4] = o1;
}

// ---------------- distributed scan: 16 blocks/batch, 1 sync/step, A hidden in wait ----------------
template <int WRITE_E>
__global__ __launch_bounds__(256) void k_scan6(
    float* eP, const float* __restrict__ adj, const float* __restrict__ GH,
    const float* __restrict__ U, const float* __restrict__ Gini, float* __restrict__ h,
    const float* __restrict__ w_ih, const float* __restrict__ b_ih,
    const float* __restrict__ w_msg, float* __restrict__ pg,
    unsigned* __restrict__ flags, int kround) {
  const int s = blockIdx.x, b = blockIdx.y, tid = threadIdx.x;
  __shared__ float wihL[16 * 1540];
  __shared__ __align__(16) float w2L[16 * 520];
  __shared__ __align__(16) float GL[16 * 132];
  __shared__ float hnL[DVV];
  __shared__ float msL[16];

  // ---- prologue: weights -> LDS ----
  for (int l = tid; l < 1536 * 16; l += 256) {
    int r = l >> 4, c = l & 15;
    wihL[c * 1540 + r] = w_ih[(size_t)r * 256 + 16 * s + c];
  }
  for (int l = tid; l < 16 * 128; l += 256) {
    int c = l >> 7, d4 = (l & 127) * 4;
    *(float4*)&w2L[c * 520 + d4] = *(const float4*)&w_msg[(size_t)(16 * s + c) * 1280 + 512 + d4];
  }
  for (int l = tid; l < 2048; l += 256) {
    int c = l & 15, j = l >> 4;
    GL[c * 132 + j] = Gini[((size_t)b * NN + j) * DEE + 16 * s + c];
  }
  float bi0 = b_ih[tid], bi1 = b_ih[tid + 256];
  float bi2 = b_ih[512 + tid], bi3 = b_ih[768 + tid];
  float bi4 = b_ih[1024 + tid], bi5 = b_ih[1280 + tid];

  const int c_loc = tid >> 4, jg = tid & 15, j0 = jg << 3;

  float4 P0, P1, A0, A1; float uu;
  float hv0, hv1, ghr0, ghr1, ghz0, ghz1, ghn0, ghn1;
  float told = 0.f, p_el = 0.f, a_el = 0.f, uuS = 0.f;
  float pa[6];

  auto loadPAU = [&](int ip) {
    size_t rE = ((size_t)(b * NN + ip) * DEE + 16 * s + c_loc) * NN + j0;
    P0 = *(const float4*)&eP[rE]; P1 = *(const float4*)&eP[rE + 4];
    size_t rA = (size_t)(b * NN + ip) * NN + j0;
    A0 = *(const float4*)&adj[rA]; A1 = *(const float4*)&adj[rA + 4];
    uu = U[(size_t)(b * NN + ip) * DEE + 16 * s + c_loc];
  };
  auto loadHG = [&](int ip) {
    size_t rH = (size_t)(b * NN + ip) * DVV;
    hv0 = h[rH + tid]; hv1 = h[rH + tid + 256];
    size_t rG = (size_t)(b * NN + ip) * 1536;
    ghr0 = GH[rG + tid]; ghr1 = GH[rG + tid + 256];
    ghz0 = GH[rG + 512 + tid]; ghz1 = GH[rG + 768 + tid];
    ghn0 = GH[rG + 1024 + tid]; ghn1 = GH[rG + 1280 + tid];
  };
  // A-bulk for step ip using current GL (col `stale` may be stale; -1 = exact).
  auto apre = [&](int ip, int stale) {
    const float* gl = &GL[c_loc * 132 + j0];
    float4 g0 = *(const float4*)&gl[0];
    float4 g1 = *(const float4*)&gl[4];
    float m0 = fmaxf(uu + g0.x + P0.x, 0.f), m1 = fmaxf(uu + g0.y + P0.y, 0.f);
    float m2 = fmaxf(uu + g0.z + P0.z, 0.f), m3 = fmaxf(uu + g0.w + P0.w, 0.f);
    float m4 = fmaxf(uu + g1.x + P1.x, 0.f), m5 = fmaxf(uu + g1.y + P1.y, 0.f);
    float m6 = fmaxf(uu + g1.z + P1.z, 0.f), m7 = fmaxf(uu + g1.w + P1.w, 0.f);
    float acc = A0.x * m0 + A0.y * m1 + A0.z * m2 + A0.w * m3
              + A1.x * m4 + A1.y * m5 + A1.z * m6 + A1.w * m7;
    if (WRITE_E) {
      size_t rE = ((size_t)(b * NN + ip) * DEE + 16 * s + c_loc) * NN + j0;
      float4 w0; w0.x = m0; w0.y = m1; w0.z = m2; w0.w = m3;
      float4 w1; w1.x = m4; w1.y = m5; w1.z = m6; w1.w = m7;
      *(float4*)&eP[rE] = w0; *(float4*)&eP[rE + 4] = w1;
    }
    if (stale >= 0 && jg == (stale >> 3)) {
      int e = stale & 7;
      p_el = sel8(P0, P1, e); a_el = sel8(A0, A1, e); uuS = uu;
      float m_el;
      switch (e) { case 0: m_el = m0; break; case 1: m_el = m1; break; case 2: m_el = m2; break;
                   case 3: m_el = m3; break; case 4: m_el = m4; break; case 5: m_el = m5; break;
                   case 6: m_el = m6; break; default: m_el = m7; }
      told = a_el * m_el;
    }
    acc += __shfl_down(acc, 8);
    acc += __shfl_down(acc, 4);
    acc += __shfl_down(acc, 2);
    acc += __shfl_down(acc, 1);
    if (jg == 0) msL[c_loc] = acc;
  };

  loadPAU(0);
  loadHG(0);
  __syncthreads();          // GL/weights ready
  apre(0, -1);              // exact msum(0)
  loadPAU(1);
  __syncthreads();          // msL(0) visible

  for (int i = 0; i < NN; ++i) {
    float* pgb = pg + (size_t)(i & 1) * PGOFF + (size_t)((b << 4) + s) * 1536;
    float* pgr = pg + (size_t)(i & 1) * PGOFF + (size_t)(b << 4) * 1536;

    // (a) B(i): partial gi from msL; keep own 6 values in regs
    {
      float ms[16];
#pragma unroll
      for (int c = 0; c < 16; ++c) ms[c] = msL[c];
#pragma unroll
      for (int u = 0; u < 6; ++u) {
        int r = tid + (u << 8);
        float v = 0.f;
#pragma unroll
        for (int c = 0; c < 16; ++c) v += wihL[c * 1540 + r] * ms[c];
        pa[u] = v;
        __hip_atomic_store(&pgb[r], v, __ATOMIC_RELAXED, __HIP_MEMORY_SCOPE_AGENT);
      }
    }
    // (b) drain pg stores
    __syncthreads();
    // (c) announce
    unsigned tgt = (unsigned)(kround * NN + i + 1);
    if (tid == 0)
      __hip_atomic_store(&flags[(((b << 4) + s) << 5)], tgt, __ATOMIC_RELAXED,
                         __HIP_MEMORY_SCOPE_AGENT);
    // (d) speculative A(i+1) with stale G col i (hidden in barrier wait)
    if (i < NN - 1) apre(i + 1, i);
    loadPAU(i < NN - 2 ? i + 2 : NN - 1);
    // (e) poll barrier(i)
    if (tid < 64) {
      unsigned* fp = &flags[(((b << 4) + (tid & 15)) << 5)];
      for (;;) {
        unsigned v = __hip_atomic_load(fp, __ATOMIC_RELAXED, __HIP_MEMORY_SCOPE_AGENT);
        if (!__any(v < tgt)) break;
        __builtin_amdgcn_s_sleep(1);
      }
    }
    __syncthreads();
    // (f) GRU(i): 15 remote slices + own regs
    {
      float sr0 = bi0 + pa[0], sr1 = bi1 + pa[1];
      float sz0 = bi2 + pa[2], sz1 = bi3 + pa[3];
      float sn0 = bi4 + pa[4], sn1 = bi5 + pa[5];
#pragma unroll
      for (int ss = 0; ss < 16; ++ss) {
        if (ss == s) continue;
        float* p = pgr + (size_t)ss * 1536;
        sr0 += __hip_atomic_load(&p[tid],        __ATOMIC_RELAXED, __HIP_MEMORY_SCOPE_AGENT);
        sr1 += __hip_atomic_load(&p[tid + 256],  __ATOMIC_RELAXED, __HIP_MEMORY_SCOPE_AGENT);
        sz0 += __hip_atomic_load(&p[512 + tid],  __ATOMIC_RELAXED, __HIP_MEMORY_SCOPE_AGENT);
        sz1 += __hip_atomic_load(&p[768 + tid],  __ATOMIC_RELAXED, __HIP_MEMORY_SCOPE_AGENT);
        sn0 += __hip_atomic_load(&p[1024 + tid], __ATOMIC_RELAXED, __HIP_MEMORY_SCOPE_AGENT);
        sn1 += __hip_atomic_load(&p[1280 + tid], __ATOMIC_RELAXED, __HIP_MEMORY_SCOPE_AGENT);
      }
      float rg0 = sigmf(sr0 + ghr0), rg1 = sigmf(sr1 + ghr1);
      float z0 = sigmf(sz0 + ghz0),  z1 = sigmf(sz1 + ghz1);
      float nv0 = tanhf_fast(sn0 + rg0 * ghn0);
      float nv1 = tanhf_fast(sn1 + rg1 * ghn1);
      float hn0 = (1.f - z0) * nv0 + z0 * hv0;
      float hn1 = (1.f - z1) * nv1 + z1 * hv1;
      hnL[tid] = hn0; hnL[tid + 256] = hn1;
      size_t rH = (size_t)(b * NN + i) * DVV;
      if ((tid >> 5) == s) h[rH + tid] = hn0;
      if (((tid + 256) >> 5) == s) h[rH + tid + 256] = hn1;
    }
    loadHG(i < NN - 1 ? i + 1 : NN - 1);
    // (g)
    __syncthreads();
    // (h) C(i): G col i
    {
      int cw = tid >> 4, dg = tid & 15;
      float acc2 = 0.f;
#pragma unroll
      for (int it = 0; it < 32; ++it) {
        int d = dg + (it << 4);
        acc2 += w2L[cw * 520 + d] * hnL[d];
      }
      acc2 += __shfl_down(acc2, 8);
      acc2 += __shfl_down(acc2, 4);
      acc2 += __shfl_down(acc2, 2);
      acc2 += __shfl_down(acc2, 1);
      if (dg == 0) GL[cw * 132 + i] = acc2;
    }
    // (i)
    __syncthreads();
    // (j) correction of msum(i+1) for the refreshed G col i
    if (i < NN - 1 && jg == (i >> 3)) {
      float gnew = GL[c_loc * 132 + i];
      float mnew = fmaxf(uuS + gnew + p_el, 0.f);
      msL[c_loc] += a_el * mnew - told;
      if (WRITE_E)
        eP[((size_t)(b * NN + i + 1) * DEE + 16 * s + c_loc) * NN + i] = mnew;
    }
    // (k)
    __syncthreads();
  }
}

// ---------------- labels ----------------
__global__ __launch_bounds__(128) void k_labels(const float* __restrict__ h, const float* __restrict__ w_ro,
                                                const float* __restrict__ b_ro, float* __restrict__ out) {
  int b = blockIdx.x >> 7, n = blockIdx.x & 127;
  __shared__ __align__(16) float hr[512];
  int tid = threadIdx.x;
  *(float4*)&hr[tid * 4] = *(const float4*)&h[(size_t)((b << 7) + n) * DVV + tid * 4];
  __syncthreads();
  if (tid < NCC) {
    const float* w = w_ro + (size_t)tid * DVV;
    float acc = b_ro[tid];
    for (int d = 0; d < DVV; d += 4) {
      float4 wv = *(const float4*)&w[d];
      acc += wv.x * hr[d] + wv.y * hr[d + 1] + wv.z * hr[d + 2] + wv.w * hr[d + 3];
    }
    out[(size_t)((b << 7) + n) * NCC + tid] = acc;
  }
}

extern "C" void kernel_launch(void* const* d_in, const int* in_sizes, int n_in,
                              void* d_out, int out_size, void* d_ws, size_t ws_size,
                              hipStream_t stream) {
  const float* edge   = (const float*)d_in[0];
  const float* node   = (const float*)d_in[1];
  const float* w_link = (const float*)d_in[6];
  const float* b_link = (const float*)d_in[7];
  const float* w_msg  = (const float*)d_in[8];
  const float* b_msg  = (const float*)d_in[9];
  const float* w_ih   = (const float*)d_in[10];
  const float* w_hh   = (const float*)d_in[11];
  const float* b_ih   = (const float*)d_in[12];
  const float* b_hh   = (const float*)d_in[13];
  const float* w_ro   = (const float*)d_in[14];
  const float* b_ro   = (const float*)d_in[15];
  float* out = (float*)d_out;
  float* ws  = (float*)d_ws;

  // workspace layout (floats)
  float* e_buf  = ws;                      // 33,554,432  (B,N,DE,N)
  float* h_buf  = e_buf + 33554432ull;     //    524,288  (B,N,DV)
  float* GH_buf = h_buf + 524288;          //  1,572,864  (B,N,1536)
  float* U_buf  = GH_buf + 1572864;        //    262,144  (B,N,256)
  float* G_buf  = U_buf + 262144;          //    262,144  (B,N,256)
  float* lE_buf = G_buf + 262144;          //    131,072  (unused, layout kept)
  float* av_buf = lE_buf + 131072;         //      2,048  (B,2,N)
  float* pg_buf = av_buf + 2048;           //    393,216  (2,B,16,1536)
  unsigned* flags = (unsigned*)(pg_buf + 2 * PGOFF);  // 4096 u32
  size_t need_bytes = 36710304ull * 4ull;
  if (ws_size < need_bytes) return;

  hipMemsetAsync(flags, 0, 4096 * sizeof(unsigned), stream);
  k_copy<<<512, 256, 0, stream>>>(node, h_buf);

  for (int k = 0; k < 3; ++k) {
    k_av<<<1024, 128, 0, stream>>>(h_buf, w_link, av_buf);
    if (k == 0) k_plogit<1><<<1024, 256, 0, stream>>>(edge, w_msg, w_link, av_buf, b_link, e_buf, out);
    else        k_plogit<0><<<1024, 256, 0, stream>>>(e_buf, w_msg, w_link, av_buf, b_link, e_buf, out);
    k_wh3<<<dim3(128, 8), 256, 0, stream>>>(w_hh, w_msg, b_hh, b_msg, h_buf, GH_buf, U_buf, G_buf);
    if (k < 2) k_scan6<1><<<dim3(SB, NB), 256, 0, stream>>>(e_buf, out, GH_buf, U_buf, G_buf, h_buf,
                                                            w_ih, b_ih, w_msg, pg_buf, flags, k);
    else       k_scan6<0><<<dim3(SB, NB), 256, 0, stream>>>(e_buf, out, GH_buf, U_buf, G_buf, h_buf,
                                                            w_ih, b_ih, w_msg, pg_buf, flags, k);
  }
  k_labels<<<1024, 128, 0, stream>>>(h_buf, w_ro, b_ro, out + 131072);
}

// Round 8
// 2785.535 us; speedup vs baseline: 1.7206x; 1.7206x over previous
//
#include <hip/hip_runtime.h>
#include <math.h>

// GPNN: B=8 graphs, N=128 nodes, DV=512, DE=256, K=3, C=117.
// R8: R7 structure; cross-block exchange (pg, flags) switched to SYSTEM-scope
// relaxed atomics (sc0+sc1 => bypass L1 and L2, read/write the L3 coherence
// point directly). Fixes the intermittent stale-cache race that failed R7's
// post-replay re-validation. No cache-maintenance instructions emitted.

#define NB 8
#define NN 128
#define DVV 512
#define DEE 256
#define NCC 117
#define SB 16
#define PGOFF 196608   // floats per pg parity buffer (8*16*1536)

__device__ __forceinline__ float sigmf(float x) {
  x = fminf(fmaxf(x, -30.f), 30.f);
  return 1.0f / (1.0f + __expf(-x));
}
__device__ __forceinline__ float tanhf_fast(float x) {
  x = fminf(fmaxf(x, -15.f), 15.f);
  float e = __expf(2.0f * x);
  return (e - 1.0f) / (e + 1.0f);
}

// ---------------- h init ----------------
__global__ __launch_bounds__(256) void k_copy(const float* __restrict__ src, float* __restrict__ dst) {
  int i = blockIdx.x * 256 + threadIdx.x;
  ((float4*)dst)[i] = ((const float4*)src)[i];
}

// ---------------- ai/aj ----------------
__global__ __launch_bounds__(128) void k_av(const float* __restrict__ h, const float* __restrict__ w_link,
                                            float* __restrict__ av) {
  int b = blockIdx.x >> 7, n = blockIdx.x & 127;
  int lane = threadIdx.x & 63, half = threadIdx.x >> 6;
  const float* hc = h + (size_t)((b << 7) + n) * DVV;
  const float* w = w_link + half * DVV;
  float acc = 0.f;
#pragma unroll
  for (int t = 0; t < 8; ++t) { int d = lane + (t << 6); acc += w[d] * hc[d]; }
#pragma unroll
  for (int off = 32; off; off >>= 1) acc += __shfl_down(acc, off);
  if (lane == 0) av[(b << 8) + half * NN + n] = acc;
}

// ---------------- per-row: adj (fused) + P = W3 @ e_row (in place), 2 c-half passes ----------------
template <int FIRST>
__global__ __launch_bounds__(256) void k_plogit(const float* src, const float* __restrict__ w_msg,
                                                const float* __restrict__ w_link,
                                                const float* __restrict__ av,
                                                const float* __restrict__ b_link,
                                                float* e_buf, float* __restrict__ adj_out) {
  int b = blockIdx.x >> 7, i = blockIdx.x & 127;
  __shared__ __align__(16) float eL[128][132];   // one c-half, 67.6 KB -> 2 blocks/CU
  int tid = threadIdx.x;
  int cg = tid >> 3, sjb = tid & 7;
  int c0 = cg * 8, jb = sjb * 16;
  float accLE = 0.f;
  float acc[8][16];
#pragma unroll
  for (int r = 0; r < 8; ++r)
#pragma unroll
    for (int u = 0; u < 16; ++u) acc[r][u] = 0.f;

  for (int p = 0; p < 2; ++p) {
    if (p) __syncthreads();
    if (FIRST) {
      const float* s0 = src + (size_t)(b * NN + i) * NN * DEE + 128 * p;
      for (int l = tid * 4; l < 16384; l += 1024) {
        int j = l >> 7, c = l & 127;
        float4 v = *(const float4*)&s0[(size_t)j * DEE + c];
        eL[c + 0][j] = v.x; eL[c + 1][j] = v.y; eL[c + 2][j] = v.z; eL[c + 3][j] = v.w;
      }
    } else {
      const float* s0 = src + (size_t)(b * NN + i) * DEE * NN + (size_t)(128 * p) * NN;
      for (int l = tid * 4; l < 16384; l += 1024) {
        int c = l >> 7, j = l & 127;
        *(float4*)&eL[c][j] = *(const float4*)&s0[l];
      }
    }
    __syncthreads();
    if (tid < NN) {
      for (int c = 0; c < 128; ++c) accLE += w_link[1024 + 128 * p + c] * eL[c][tid];
    }
    for (int c = 0; c < 128; c += 4) {
      float4 w[8];
#pragma unroll
      for (int r = 0; r < 8; ++r)
        w[r] = *(const float4*)&w_msg[(size_t)(c0 + r) * 1280 + 1024 + 128 * p + c];
#pragma unroll
      for (int cc = 0; cc < 4; ++cc) {
        float4 e0 = *(const float4*)&eL[c + cc][jb];
        float4 e1 = *(const float4*)&eL[c + cc][jb + 4];
        float4 e2 = *(const float4*)&eL[c + cc][jb + 8];
        float4 e3 = *(const float4*)&eL[c + cc][jb + 12];
#pragma unroll
        for (int r = 0; r < 8; ++r) {
          float wv = ((const float*)&w[r])[cc];
          acc[r][0] += wv * e0.x;  acc[r][1] += wv * e0.y;  acc[r][2] += wv * e0.z;  acc[r][3] += wv * e0.w;
          acc[r][4] += wv * e1.x;  acc[r][5] += wv * e1.y;  acc[r][6] += wv * e1.z;  acc[r][7] += wv * e1.w;
          acc[r][8] += wv * e2.x;  acc[r][9] += wv * e2.y;  acc[r][10] += wv * e2.z; acc[r][11] += wv * e2.w;
          acc[r][12] += wv * e3.x; acc[r][13] += wv * e3.y; acc[r][14] += wv * e3.z; acc[r][15] += wv * e3.w;
        }
      }
    }
  }
#pragma unroll
  for (int r = 0; r < 8; ++r)
#pragma unroll
    for (int u4 = 0; u4 < 4; ++u4) {
      float4 o; o.x = acc[r][u4 * 4]; o.y = acc[r][u4 * 4 + 1]; o.z = acc[r][u4 * 4 + 2]; o.w = acc[r][u4 * 4 + 3];
      *(float4*)&e_buf[((size_t)(b * NN + i) * DEE + c0 + r) * NN + jb + u4 * 4] = o;
    }
  if (tid < NN) {
    float x = av[(b << 8) + NN + i] + av[(b << 8) + tid] + accLE + b_link[0];
    adj_out[((size_t)b * NN + i) * NN + tid] = sigmf(x);
  }
}

// ---------------- merged W@h kernel: GH (96 blk) + U (16) + G (16) ----------------
__global__ __launch_bounds__(256) void k_wh3(const float* __restrict__ w_hh, const float* __restrict__ w_msg,
                                             const float* __restrict__ b_hh, const float* __restrict__ b_msg,
                                             const float* __restrict__ h, float* __restrict__ GHo,
                                             float* __restrict__ Uo, float* __restrict__ Go) {
  int bx = blockIdx.x, b = blockIdx.y;
  const float* W; const float* bias; float* out; int ldw, R, r0;
  if (bx < 96)       { W = w_hh;        ldw = 512;  R = 1536; bias = b_hh;   out = GHo; r0 = bx * 16; }
  else if (bx < 112) { W = w_msg;       ldw = 1280; R = 256;  bias = b_msg;  out = Uo;  r0 = (bx - 96) * 16; }
  else               { W = w_msg + 512; ldw = 1280; R = 256;  bias = nullptr; out = Go; r0 = (bx - 112) * 16; }
  __shared__ float hT[128][129];
  __shared__ float wT[16][129];
  __shared__ float outT[16][129];
  int tid = threadIdx.x;
  int n = tid & 127, rr = tid >> 7;
  float acc8[8] = {0, 0, 0, 0, 0, 0, 0, 0};
  for (int dc = 0; dc < DVV; dc += 128) {
    if (dc) __syncthreads();
    for (int l = tid * 4; l < 16384; l += 1024) {
      int nn = l >> 7, d = l & 127;
      float4 v = *(const float4*)&h[((size_t)(b << 7) + nn) * DVV + dc + d];
      hT[d + 0][nn] = v.x; hT[d + 1][nn] = v.y; hT[d + 2][nn] = v.z; hT[d + 3][nn] = v.w;
    }
    for (int l = tid; l < 2048; l += 256) {
      int r = l >> 7, d = l & 127;
      wT[r][d] = W[(size_t)(r0 + r) * ldw + dc + d];
    }
    __syncthreads();
    for (int d = 0; d < 128; ++d) {
      float hval = hT[d][n];
#pragma unroll
      for (int r8 = 0; r8 < 8; ++r8) acc8[r8] += wT[rr * 8 + r8][d] * hval;
    }
  }
#pragma unroll
  for (int r8 = 0; r8 < 8; ++r8) {
    int r = rr * 8 + r8;
    outT[r][n] = acc8[r8] + (bias ? bias[r0 + r] : 0.0f);
  }
  __syncthreads();
  int n2 = tid >> 1, q = tid & 1;
  size_t base = ((size_t)(b << 7) + n2) * R + r0 + q * 8;
  float4 o0; o0.x = outT[q * 8 + 0][n2]; o0.y = outT[q * 8 + 1][n2]; o0.z = outT[q * 8 + 2][n2]; o0.w = outT[q * 8 + 3][n2];
  float4 o1; o1.x = outT[q * 8 + 4][n2]; o1.y = outT[q * 8 + 5][n2]; o1.z = outT[q * 8 + 6][n2]; o1.w = outT[q * 8 + 7][n2];
  *(float4*)&out[base] = o0;
  *(float4*)&out[base + 4] = o1;
}

// ---------------- distributed scan (R5 schedule; SYSTEM-scope exchange) ----------------
template <int WRITE_E>
__global__ __launch_bounds__(256) void k_scan8(
    float* eP, const float* __restrict__ adj, const float* __restrict__ GH,
    const float* __restrict__ U, const float* __restrict__ Gini, float* __restrict__ h,
    const float* __restrict__ w_ih, const float* __restrict__ b_ih,
    const float* __restrict__ w_msg, float* __restrict__ pg,
    unsigned* __restrict__ flags, int kround) {
  const int s = blockIdx.x, b = blockIdx.y, tid = threadIdx.x;
  __shared__ float wihL[16 * 1540];
  __shared__ __align__(16) float w2L[16 * 520];
  __shared__ __align__(16) float GL[16 * 132];
  __shared__ float hnL[DVV];
  __shared__ float msL[16];

  for (int l = tid; l < 1536 * 16; l += 256) {
    int r = l >> 4, c = l & 15;
    wihL[c * 1540 + r] = w_ih[(size_t)r * 256 + 16 * s + c];
  }
  for (int l = tid; l < 16 * 128; l += 256) {
    int c = l >> 7, d4 = (l & 127) * 4;
    *(float4*)&w2L[c * 520 + d4] = *(const float4*)&w_msg[(size_t)(16 * s + c) * 1280 + 512 + d4];
  }
  for (int l = tid; l < 2048; l += 256) {
    int c = l & 15, j = l >> 4;
    GL[c * 132 + j] = Gini[((size_t)b * NN + j) * DEE + 16 * s + c];
  }
  float bi0 = b_ih[tid], bi1 = b_ih[tid + 256];
  float bi2 = b_ih[512 + tid], bi3 = b_ih[768 + tid];
  float bi4 = b_ih[1024 + tid], bi5 = b_ih[1280 + tid];

  const int c_loc = tid >> 4, jg = tid & 15, j0 = jg << 3;

  float4 P0, P1, A0, A1; float uu;
  float hv0, hv1, ghr0, ghr1, ghz0, ghz1, ghn0, ghn1;
  {
    size_t rE = ((size_t)(b * NN + 0) * DEE + 16 * s + c_loc) * NN + j0;
    P0 = *(const float4*)&eP[rE]; P1 = *(const float4*)&eP[rE + 4];
    size_t rA = (size_t)(b * NN + 0) * NN + j0;
    A0 = *(const float4*)&adj[rA]; A1 = *(const float4*)&adj[rA + 4];
    uu = U[(size_t)(b * NN + 0) * DEE + 16 * s + c_loc];
    size_t rH = (size_t)(b * NN + 0) * DVV;
    hv0 = h[rH + tid]; hv1 = h[rH + tid + 256];
    size_t rG = (size_t)(b * NN + 0) * 1536;
    ghr0 = GH[rG + tid]; ghr1 = GH[rG + tid + 256];
    ghz0 = GH[rG + 512 + tid]; ghz1 = GH[rG + 768 + tid];
    ghn0 = GH[rG + 1024 + tid]; ghn1 = GH[rG + 1280 + tid];
  }

  for (int i = 0; i < NN; ++i) {
    float* pgb = pg + (size_t)(i & 1) * PGOFF + (size_t)((b << 4) + s) * 1536;
    float* pgr = pg + (size_t)(i & 1) * PGOFF + (size_t)(b << 4) * 1536;
    __syncthreads();   // (1)

    // ---- Phase A ----
    float acc;
    {
      const float* gl = &GL[c_loc * 132 + j0];
      float4 g0 = *(const float4*)&gl[0];
      float4 g1 = *(const float4*)&gl[4];
      float m0 = fmaxf(uu + g0.x + P0.x, 0.f), m1 = fmaxf(uu + g0.y + P0.y, 0.f);
      float m2 = fmaxf(uu + g0.z + P0.z, 0.f), m3 = fmaxf(uu + g0.w + P0.w, 0.f);
      float m4 = fmaxf(uu + g1.x + P1.x, 0.f), m5 = fmaxf(uu + g1.y + P1.y, 0.f);
      float m6 = fmaxf(uu + g1.z + P1.z, 0.f), m7 = fmaxf(uu + g1.w + P1.w, 0.f);
      acc = A0.x * m0 + A0.y * m1 + A0.z * m2 + A0.w * m3
          + A1.x * m4 + A1.y * m5 + A1.z * m6 + A1.w * m7;
      if (WRITE_E) {
        size_t rE = ((size_t)(b * NN + i) * DEE + 16 * s + c_loc) * NN + j0;
        float4 w0; w0.x = m0; w0.y = m1; w0.z = m2; w0.w = m3;
        float4 w1; w1.x = m4; w1.y = m5; w1.z = m6; w1.w = m7;
        *(float4*)&eP[rE] = w0; *(float4*)&eP[rE + 4] = w1;
      }
    }
    {
      int in = (i < NN - 1) ? i + 1 : NN - 1;
      size_t rE = ((size_t)(b * NN + in) * DEE + 16 * s + c_loc) * NN + j0;
      P0 = *(const float4*)&eP[rE]; P1 = *(const float4*)&eP[rE + 4];
      size_t rA = (size_t)(b * NN + in) * NN + j0;
      A0 = *(const float4*)&adj[rA]; A1 = *(const float4*)&adj[rA + 4];
      uu = U[(size_t)(b * NN + in) * DEE + 16 * s + c_loc];
    }
    acc += __shfl_down(acc, 8);
    acc += __shfl_down(acc, 4);
    acc += __shfl_down(acc, 2);
    acc += __shfl_down(acc, 1);
    if (jg == 0) msL[c_loc] = acc;
    __syncthreads();   // (2)

    // ---- Phase B (system-scope sc0+sc1 stores) ----
    {
      float ms[16];
#pragma unroll
      for (int c = 0; c < 16; ++c) ms[c] = msL[c];
#pragma unroll
      for (int u = 0; u < 6; ++u) {
        int r = tid + (u << 8);
        float pa = 0.f;
#pragma unroll
        for (int c = 0; c < 16; ++c) pa += wihL[c * 1540 + r] * ms[c];
        __hip_atomic_store(&pgb[r], pa, __ATOMIC_RELAXED, __HIP_MEMORY_SCOPE_SYSTEM);
      }
    }

    // ---- flag-array barrier (system-scope) ----
    {
      unsigned tgt = (unsigned)(kround * NN + i + 1);
      __syncthreads();   // (3) vmcnt drain: pg stores committed at coherence point
      if (tid < 64) {
        if (tid == 0)
          __hip_atomic_store(&flags[(((b << 4) + s) << 5)], tgt, __ATOMIC_RELAXED,
                             __HIP_MEMORY_SCOPE_SYSTEM);
        unsigned* fp = &flags[(((b << 4) + (tid & 15)) << 5)];
        for (;;) {
          unsigned v = __hip_atomic_load(fp, __ATOMIC_RELAXED, __HIP_MEMORY_SCOPE_SYSTEM);
          if (!__any(v < tgt)) break;
          __builtin_amdgcn_s_sleep(1);
        }
      }
      __syncthreads();   // (4)
    }

    // ---- GRU (system-scope sc0+sc1 loads — bypass L1/L2, read L3 directly) ----
    {
      float sr0 = bi0, sr1 = bi1, sz0 = bi2, sz1 = bi3, sn0 = bi4, sn1 = bi5;
#pragma unroll
      for (int ss = 0; ss < 16; ++ss) {
        float* p = pgr + (size_t)ss * 1536;
        sr0 += __hip_atomic_load(&p[tid],        __ATOMIC_RELAXED, __HIP_MEMORY_SCOPE_SYSTEM);
        sr1 += __hip_atomic_load(&p[tid + 256],  __ATOMIC_RELAXED, __HIP_MEMORY_SCOPE_SYSTEM);
        sz0 += __hip_atomic_load(&p[512 + tid],  __ATOMIC_RELAXED, __HIP_MEMORY_SCOPE_SYSTEM);
        sz1 += __hip_atomic_load(&p[768 + tid],  __ATOMIC_RELAXED, __HIP_MEMORY_SCOPE_SYSTEM);
        sn0 += __hip_atomic_load(&p[1024 + tid], __ATOMIC_RELAXED, __HIP_MEMORY_SCOPE_SYSTEM);
        sn1 += __hip_atomic_load(&p[1280 + tid], __ATOMIC_RELAXED, __HIP_MEMORY_SCOPE_SYSTEM);
      }
      float rg0 = sigmf(sr0 + ghr0), rg1 = sigmf(sr1 + ghr1);
      float z0 = sigmf(sz0 + ghz0),  z1 = sigmf(sz1 + ghz1);
      float nv0 = tanhf_fast(sn0 + rg0 * ghn0);
      float nv1 = tanhf_fast(sn1 + rg1 * ghn1);
      float hn0 = (1.f - z0) * nv0 + z0 * hv0;
      float hn1 = (1.f - z1) * nv1 + z1 * hv1;
      hnL[tid] = hn0; hnL[tid + 256] = hn1;
      size_t rH = (size_t)(b * NN + i) * DVV;
      if ((tid >> 5) == s) h[rH + tid] = hn0;
      if (((tid + 256) >> 5) == s) h[rH + tid + 256] = hn1;
    }
    {
      int in = (i < NN - 1) ? i + 1 : NN - 1;
      size_t rH = (size_t)(b * NN + in) * DVV;
      hv0 = h[rH + tid]; hv1 = h[rH + tid + 256];
      size_t rG = (size_t)(b * NN + in) * 1536;
      ghr0 = GH[rG + tid]; ghr1 = GH[rG + tid + 256];
      ghz0 = GH[rG + 512 + tid]; ghz1 = GH[rG + 768 + tid];
      ghn0 = GH[rG + 1024 + tid]; ghn1 = GH[rG + 1280 + tid];
    }
    __syncthreads();   // (5)

    // ---- Phase C ----
    {
      int cw = tid >> 4, dg = tid & 15;
      float acc2 = 0.f;
#pragma unroll
      for (int it = 0; it < 32; ++it) {
        int d = dg + (it << 4);
        acc2 += w2L[cw * 520 + d] * hnL[d];
      }
      acc2 += __shfl_down(acc2, 8);
      acc2 += __shfl_down(acc2, 4);
      acc2 += __shfl_down(acc2, 2);
      acc2 += __shfl_down(acc2, 1);
      if (dg == 0) GL[cw * 132 + i] = acc2;
    }
  }
}

// ---------------- labels ----------------
__global__ __launch_bounds__(128) void k_labels(const float* __restrict__ h, const float* __restrict__ w_ro,
                                                const float* __restrict__ b_ro, float* __restrict__ out) {
  int b = blockIdx.x >> 7, n = blockIdx.x & 127;
  __shared__ __align__(16) float hr[512];
  int tid = threadIdx.x;
  *(float4*)&hr[tid * 4] = *(const float4*)&h[(size_t)((b << 7) + n) * DVV + tid * 4];
  __syncthreads();
  if (tid < NCC) {
    const float* w = w_ro + (size_t)tid * DVV;
    float acc = b_ro[tid];
    for (int d = 0; d < DVV; d += 4) {
      float4 wv = *(const float4*)&w[d];
      acc += wv.x * hr[d] + wv.y * hr[d + 1] + wv.z * hr[d + 2] + wv.w * hr[d + 3];
    }
    out[(size_t)((b << 7) + n) * NCC + tid] = acc;
  }
}

extern "C" void kernel_launch(void* const* d_in, const int* in_sizes, int n_in,
                              void* d_out, int out_size, void* d_ws, size_t ws_size,
                              hipStream_t stream) {
  const float* edge   = (const float*)d_in[0];
  const float* node   = (const float*)d_in[1];
  const float* w_link = (const float*)d_in[6];
  const float* b_link = (const float*)d_in[7];
  const float* w_msg  = (const float*)d_in[8];
  const float* b_msg  = (const float*)d_in[9];
  const float* w_ih   = (const float*)d_in[10];
  const float* w_hh   = (const float*)d_in[11];
  const float* b_ih   = (const float*)d_in[12];
  const float* b_hh   = (const float*)d_in[13];
  const float* w_ro   = (const float*)d_in[14];
  const float* b_ro   = (const float*)d_in[15];
  float* out = (float*)d_out;
  float* ws  = (float*)d_ws;

  float* e_buf  = ws;                      // 33,554,432  (B,N,DE,N)
  float* h_buf  = e_buf + 33554432ull;     //    524,288  (B,N,DV)
  float* GH_buf = h_buf + 524288;          //  1,572,864  (B,N,1536)
  float* U_buf  = GH_buf + 1572864;        //    262,144  (B,N,256)
  float* G_buf  = U_buf + 262144;          //    262,144  (B,N,256)
  float* lE_buf = G_buf + 262144;          //    131,072  (unused, layout kept)
  float* av_buf = lE_buf + 131072;         //      2,048  (B,2,N)
  float* pg_buf = av_buf + 2048;           //    393,216  (2,B,16,1536)
  unsigned* flags = (unsigned*)(pg_buf + 2 * PGOFF);  // 4096 u32
  size_t need_bytes = 36710304ull * 4ull;
  if (ws_size < need_bytes) return;

  hipMemsetAsync(flags, 0, 4096 * sizeof(unsigned), stream);
  k_copy<<<512, 256, 0, stream>>>(node, h_buf);

  for (int k = 0; k < 3; ++k) {
    k_av<<<1024, 128, 0, stream>>>(h_buf, w_link, av_buf);
    if (k == 0) k_plogit<1><<<1024, 256, 0, stream>>>(edge, w_msg, w_link, av_buf, b_link, e_buf, out);
    else        k_plogit<0><<<1024, 256, 0, stream>>>(e_buf, w_msg, w_link, av_buf, b_link, e_buf, out);
    k_wh3<<<dim3(128, 8), 256, 0, stream>>>(w_hh, w_msg, b_hh, b_msg, h_buf, GH_buf, U_buf, G_buf);
    if (k < 2) k_scan8<1><<<dim3(SB, NB), 256, 0, stream>>>(e_buf, out, GH_buf, U_buf, G_buf, h_buf,
                                                            w_ih, b_ih, w_msg, pg_buf, flags, k);
    else       k_scan8<0><<<dim3(SB, NB), 256, 0, stream>>>(e_buf, out, GH_buf, U_buf, G_buf, h_buf,
                                                            w_ih, b_ih, w_msg, pg_buf, flags, k);
  }
  k_labels<<<1024, 128, 0, stream>>>(h_buf, w_ro, b_ro, out + 131072);
}

// Round 9
// 2313.267 us; speedup vs baseline: 2.0718x; 1.2042x over previous
//
#include <hip/hip_runtime.h>
#include <math.h>

// GPNN: B=8 graphs, N=128 nodes, DV=512, DE=256, K=3, C=117.
// R9: plogit GEMM (P = W3 @ e_row) moved to bf16 MFMA (16x16x32), fp32 accum,
// e-tile staged to LDS bf16 [j][c]. Scan = R8's proven k_scan8 (verbatim).

#define NB 8
#define NN 128
#define DVV 512
#define DEE 256
#define NCC 117
#define SB 16
#define PGOFF 196608   // floats per pg parity buffer (8*16*1536)

typedef __attribute__((ext_vector_type(8))) short short8;
typedef __attribute__((ext_vector_type(4))) float f32x4;

__device__ __forceinline__ float sigmf(float x) {
  x = fminf(fmaxf(x, -30.f), 30.f);
  return 1.0f / (1.0f + __expf(-x));
}
__device__ __forceinline__ float tanhf_fast(float x) {
  x = fminf(fmaxf(x, -15.f), 15.f);
  float e = __expf(2.0f * x);
  return (e - 1.0f) / (e + 1.0f);
}
__device__ __forceinline__ unsigned short f2bf(float f) {
  union { float f; unsigned u; } v; v.f = f;
  unsigned u = v.u + 0x7FFFu + ((v.u >> 16) & 1u);
  return (unsigned short)(u >> 16);
}

// ---------------- h init ----------------
__global__ __launch_bounds__(256) void k_copy(const float* __restrict__ src, float* __restrict__ dst) {
  int i = blockIdx.x * 256 + threadIdx.x;
  ((float4*)dst)[i] = ((const float4*)src)[i];
}

// ---------------- W3 -> bf16 (once) ----------------
__global__ __launch_bounds__(256) void k_cvtw(const float* __restrict__ w_msg,
                                              unsigned short* __restrict__ w3b) {
  int idx = blockIdx.x * 256 + threadIdx.x;      // 65536
  int r = idx >> 8, c = idx & 255;
  w3b[idx] = f2bf(w_msg[(size_t)r * 1280 + 1024 + c]);
}

// ---------------- ai/aj ----------------
__global__ __launch_bounds__(128) void k_av(const float* __restrict__ h, const float* __restrict__ w_link,
                                            float* __restrict__ av) {
  int b = blockIdx.x >> 7, n = blockIdx.x & 127;
  int lane = threadIdx.x & 63, half = threadIdx.x >> 6;
  const float* hc = h + (size_t)((b << 7) + n) * DVV;
  const float* w = w_link + half * DVV;
  float acc = 0.f;
#pragma unroll
  for (int t = 0; t < 8; ++t) { int d = lane + (t << 6); acc += w[d] * hc[d]; }
#pragma unroll
  for (int off = 32; off; off >>= 1) acc += __shfl_down(acc, off);
  if (lane == 0) av[(b << 8) + half * NN + n] = acc;
}

// ---------------- per-row: adj (fused) + P = W3 @ e_row via bf16 MFMA ----------------
// LDS: e-tile bf16 [j][c], row pad 264 ushort (528B, 16B-aligned) = 67.6 KB.
// 4 waves; wave w owns r-rows [64w, 64w+64): acc[4 r-tiles][8 j-tiles] f32x4.
template <int FIRST>
__global__ __launch_bounds__(256) void k_plogit_mfma(
    const float* src, const unsigned short* __restrict__ w3b,
    const float* __restrict__ w_link, const float* __restrict__ av,
    const float* __restrict__ b_link, float* e_buf, float* __restrict__ adj_out) {
  int b = blockIdx.x >> 7, i = blockIdx.x & 127;
  __shared__ unsigned short eL[128 * 264];
  int tid = threadIdx.x;

  // ---- stage e tile -> bf16 LDS [j][c] ----
  if (FIRST) {
    // edge[b][i][j][c] fp32: c contiguous
    const float* s0 = src + (size_t)(b * NN + i) * NN * DEE;
    int j = tid >> 6, c0 = (tid & 63) * 4;
#pragma unroll 4
    for (int it = 0; it < 32; ++it, j += 4) {
      float4 v = *(const float4*)&s0[(size_t)j * DEE + c0];
      unsigned long long pk = (unsigned long long)f2bf(v.x)
                            | ((unsigned long long)f2bf(v.y) << 16)
                            | ((unsigned long long)f2bf(v.z) << 32)
                            | ((unsigned long long)f2bf(v.w) << 48);
      *(unsigned long long*)&eL[j * 264 + c0] = pk;
    }
  } else {
    // e[c][j] fp32: 4x4 in-register transpose
    const float* s0 = src + (size_t)(b * NN + i) * DEE * NN;
    int j0 = (tid & 31) * 4, c0b = (tid >> 5) * 4;
#pragma unroll
    for (int it = 0; it < 8; ++it) {
      int c0 = c0b + 32 * it;
      float4 r0 = *(const float4*)&s0[(size_t)(c0 + 0) * NN + j0];
      float4 r1 = *(const float4*)&s0[(size_t)(c0 + 1) * NN + j0];
      float4 r2 = *(const float4*)&s0[(size_t)(c0 + 2) * NN + j0];
      float4 r3 = *(const float4*)&s0[(size_t)(c0 + 3) * NN + j0];
      unsigned long long p0 = (unsigned long long)f2bf(r0.x) | ((unsigned long long)f2bf(r1.x) << 16)
                            | ((unsigned long long)f2bf(r2.x) << 32) | ((unsigned long long)f2bf(r3.x) << 48);
      unsigned long long p1 = (unsigned long long)f2bf(r0.y) | ((unsigned long long)f2bf(r1.y) << 16)
                            | ((unsigned long long)f2bf(r2.y) << 32) | ((unsigned long long)f2bf(r3.y) << 48);
      unsigned long long p2 = (unsigned long long)f2bf(r0.z) | ((unsigned long long)f2bf(r1.z) << 16)
                            | ((unsigned long long)f2bf(r2.z) << 32) | ((unsigned long long)f2bf(r3.z) << 48);
      unsigned long long p3 = (unsigned long long)f2bf(r0.w) | ((unsigned long long)f2bf(r1.w) << 16)
                            | ((unsigned long long)f2bf(r2.w) << 32) | ((unsigned long long)f2bf(r3.w) << 48);
      *(unsigned long long*)&eL[(j0 + 0) * 264 + c0] = p0;
      *(unsigned long long*)&eL[(j0 + 1) * 264 + c0] = p1;
      *(unsigned long long*)&eL[(j0 + 2) * 264 + c0] = p2;
      *(unsigned long long*)&eL[(j0 + 3) * 264 + c0] = p3;
    }
  }
  __syncthreads();

  // ---- logitE per j (threads 0..127) ----
  float accLE = 0.f;
  if (tid < NN) {
    const unsigned short* row = &eL[tid * 264];
    for (int c = 0; c < DEE; ++c) {
      union { unsigned u; float f; } cv; cv.u = ((unsigned)row[c]) << 16;
      accLE += w_link[1024 + c] * cv.f;
    }
  }

  // ---- MFMA main loop ----
  const int w = tid >> 6, l = tid & 63;
  const int lm = l & 15, lg = l >> 4;
  f32x4 acc[4][8];
#pragma unroll
  for (int a = 0; a < 4; ++a)
#pragma unroll
    for (int jt = 0; jt < 8; ++jt) acc[a][jt] = (f32x4){0.f, 0.f, 0.f, 0.f};

#pragma unroll
  for (int kk = 0; kk < 8; ++kk) {
    short8 afr[4];
#pragma unroll
    for (int a = 0; a < 4; ++a)
      afr[a] = *(const short8*)&w3b[(size_t)(64 * w + 16 * a + lm) * 256 + 32 * kk + 8 * lg];
#pragma unroll
    for (int jt = 0; jt < 8; ++jt) {
      short8 bfr = *(const short8*)&eL[(16 * jt + lm) * 264 + 32 * kk + 8 * lg];
#pragma unroll
      for (int a = 0; a < 4; ++a)
        acc[a][jt] = __builtin_amdgcn_mfma_f32_16x16x32_bf16(afr[a], bfr, acc[a][jt], 0, 0, 0);
    }
  }

  // ---- epilogue: P (fp32, [c][j]) ----
  float* Pout = e_buf + (size_t)(b * NN + i) * DEE * NN;
#pragma unroll
  for (int a = 0; a < 4; ++a) {
    int rbase = 64 * w + 16 * a + 4 * lg;
#pragma unroll
    for (int jt = 0; jt < 8; ++jt) {
      int j = 16 * jt + lm;
#pragma unroll
      for (int q = 0; q < 4; ++q)
        Pout[(size_t)(rbase + q) * NN + j] = acc[a][jt][q];
    }
  }
  // ---- adj row (fused) ----
  if (tid < NN) {
    float x = av[(b << 8) + NN + i] + av[(b << 8) + tid] + accLE + b_link[0];
    adj_out[((size_t)b * NN + i) * NN + tid] = sigmf(x);
  }
}

// ---------------- merged W@h kernel: GH (96 blk) + U (16) + G (16) ----------------
__global__ __launch_bounds__(256) void k_wh3(const float* __restrict__ w_hh, const float* __restrict__ w_msg,
                                             const float* __restrict__ b_hh, const float* __restrict__ b_msg,
                                             const float* __restrict__ h, float* __restrict__ GHo,
                                             float* __restrict__ Uo, float* __restrict__ Go) {
  int bx = blockIdx.x, b = blockIdx.y;
  const float* W; const float* bias; float* out; int ldw, R, r0;
  if (bx < 96)       { W = w_hh;        ldw = 512;  R = 1536; bias = b_hh;   out = GHo; r0 = bx * 16; }
  else if (bx < 112) { W = w_msg;       ldw = 1280; R = 256;  bias = b_msg;  out = Uo;  r0 = (bx - 96) * 16; }
  else               { W = w_msg + 512; ldw = 1280; R = 256;  bias = nullptr; out = Go; r0 = (bx - 112) * 16; }
  __shared__ float hT[128][129];
  __shared__ float wT[16][129];
  __shared__ float outT[16][129];
  int tid = threadIdx.x;
  int n = tid & 127, rr = tid >> 7;
  float acc8[8] = {0, 0, 0, 0, 0, 0, 0, 0};
  for (int dc = 0; dc < DVV; dc += 128) {
    if (dc) __syncthreads();
    for (int l = tid * 4; l < 16384; l += 1024) {
      int nn = l >> 7, d = l & 127;
      float4 v = *(const float4*)&h[((size_t)(b << 7) + nn) * DVV + dc + d];
      hT[d + 0][nn] = v.x; hT[d + 1][nn] = v.y; hT[d + 2][nn] = v.z; hT[d + 3][nn] = v.w;
    }
    for (int l = tid; l < 2048; l += 256) {
      int r = l >> 7, d = l & 127;
      wT[r][d] = W[(size_t)(r0 + r) * ldw + dc + d];
    }
    __syncthreads();
    for (int d = 0; d < 128; ++d) {
      float hval = hT[d][n];
#pragma unroll
      for (int r8 = 0; r8 < 8; ++r8) acc8[r8] += wT[rr * 8 + r8][d] * hval;
    }
  }
#pragma unroll
  for (int r8 = 0; r8 < 8; ++r8) {
    int r = rr * 8 + r8;
    outT[r][n] = acc8[r8] + (bias ? bias[r0 + r] : 0.0f);
  }
  __syncthreads();
  int n2 = tid >> 1, q = tid & 1;
  size_t base = ((size_t)(b << 7) + n2) * R + r0 + q * 8;
  float4 o0; o0.x = outT[q * 8 + 0][n2]; o0.y = outT[q * 8 + 1][n2]; o0.z = outT[q * 8 + 2][n2]; o0.w = outT[q * 8 + 3][n2];
  float4 o1; o1.x = outT[q * 8 + 4][n2]; o1.y = outT[q * 8 + 5][n2]; o1.z = outT[q * 8 + 6][n2]; o1.w = outT[q * 8 + 7][n2];
  *(float4*)&out[base] = o0;
  *(float4*)&out[base + 4] = o1;
}

// ---------------- distributed scan (R8, verbatim) ----------------
template <int WRITE_E>
__global__ __launch_bounds__(256) void k_scan8(
    float* eP, const float* __restrict__ adj, const float* __restrict__ GH,
    const float* __restrict__ U, const float* __restrict__ Gini, float* __restrict__ h,
    const float* __restrict__ w_ih, const float* __restrict__ b_ih,
    const float* __restrict__ w_msg, float* __restrict__ pg,
    unsigned* __restrict__ flags, int kround) {
  const int s = blockIdx.x, b = blockIdx.y, tid = threadIdx.x;
  __shared__ float wihL[16 * 1540];
  __shared__ __align__(16) float w2L[16 * 520];
  __shared__ __align__(16) float GL[16 * 132];
  __shared__ float hnL[DVV];
  __shared__ float msL[16];

  for (int l = tid; l < 1536 * 16; l += 256) {
    int r = l >> 4, c = l & 15;
    wihL[c * 1540 + r] = w_ih[(size_t)r * 256 + 16 * s + c];
  }
  for (int l = tid; l < 16 * 128; l += 256) {
    int c = l >> 7, d4 = (l & 127) * 4;
    *(float4*)&w2L[c * 520 + d4] = *(const float4*)&w_msg[(size_t)(16 * s + c) * 1280 + 512 + d4];
  }
  for (int l = tid; l < 2048; l += 256) {
    int c = l & 15, j = l >> 4;
    GL[c * 132 + j] = Gini[((size_t)b * NN + j) * DEE + 16 * s + c];
  }
  float bi0 = b_ih[tid], bi1 = b_ih[tid + 256];
  float bi2 = b_ih[512 + tid], bi3 = b_ih[768 + tid];
  float bi4 = b_ih[1024 + tid], bi5 = b_ih[1280 + tid];

  const int c_loc = tid >> 4, jg = tid & 15, j0 = jg << 3;

  float4 P0, P1, A0, A1; float uu;
  float hv0, hv1, ghr0, ghr1, ghz0, ghz1, ghn0, ghn1;
  {
    size_t rE = ((size_t)(b * NN + 0) * DEE + 16 * s + c_loc) * NN + j0;
    P0 = *(const float4*)&eP[rE]; P1 = *(const float4*)&eP[rE + 4];
    size_t rA = (size_t)(b * NN + 0) * NN + j0;
    A0 = *(const float4*)&adj[rA]; A1 = *(const float4*)&adj[rA + 4];
    uu = U[(size_t)(b * NN + 0) * DEE + 16 * s + c_loc];
    size_t rH = (size_t)(b * NN + 0) * DVV;
    hv0 = h[rH + tid]; hv1 = h[rH + tid + 256];
    size_t rG = (size_t)(b * NN + 0) * 1536;
    ghr0 = GH[rG + tid]; ghr1 = GH[rG + tid + 256];
    ghz0 = GH[rG + 512 + tid]; ghz1 = GH[rG + 768 + tid];
    ghn0 = GH[rG + 1024 + tid]; ghn1 = GH[rG + 1280 + tid];
  }

  for (int i = 0; i < NN; ++i) {
    float* pgb = pg + (size_t)(i & 1) * PGOFF + (size_t)((b << 4) + s) * 1536;
    float* pgr = pg + (size_t)(i & 1) * PGOFF + (size_t)(b << 4) * 1536;
    __syncthreads();   // (1)

    // ---- Phase A ----
    float acc;
    {
      const float* gl = &GL[c_loc * 132 + j0];
      float4 g0 = *(const float4*)&gl[0];
      float4 g1 = *(const float4*)&gl[4];
      float m0 = fmaxf(uu + g0.x + P0.x, 0.f), m1 = fmaxf(uu + g0.y + P0.y, 0.f);
      float m2 = fmaxf(uu + g0.z + P0.z, 0.f), m3 = fmaxf(uu + g0.w + P0.w, 0.f);
      float m4 = fmaxf(uu + g1.x + P1.x, 0.f), m5 = fmaxf(uu + g1.y + P1.y, 0.f);
      float m6 = fmaxf(uu + g1.z + P1.z, 0.f), m7 = fmaxf(uu + g1.w + P1.w, 0.f);
      acc = A0.x * m0 + A0.y * m1 + A0.z * m2 + A0.w * m3
          + A1.x * m4 + A1.y * m5 + A1.z * m6 + A1.w * m7;
      if (WRITE_E) {
        size_t rE = ((size_t)(b * NN + i) * DEE + 16 * s + c_loc) * NN + j0;
        float4 w0; w0.x = m0; w0.y = m1; w0.z = m2; w0.w = m3;
        float4 w1; w1.x = m4; w1.y = m5; w1.z = m6; w1.w = m7;
        *(float4*)&eP[rE] = w0; *(float4*)&eP[rE + 4] = w1;
      }
    }
    {
      int in = (i < NN - 1) ? i + 1 : NN - 1;
      size_t rE = ((size_t)(b * NN + in) * DEE + 16 * s + c_loc) * NN + j0;
      P0 = *(const float4*)&eP[rE]; P1 = *(const float4*)&eP[rE + 4];
      size_t rA = (size_t)(b * NN + in) * NN + j0;
      A0 = *(const float4*)&adj[rA]; A1 = *(const float4*)&adj[rA + 4];
      uu = U[(size_t)(b * NN + in) * DEE + 16 * s + c_loc];
    }
    acc += __shfl_down(acc, 8);
    acc += __shfl_down(acc, 4);
    acc += __shfl_down(acc, 2);
    acc += __shfl_down(acc, 1);
    if (jg == 0) msL[c_loc] = acc;
    __syncthreads();   // (2)

    // ---- Phase B (system-scope stores) ----
    {
      float ms[16];
#pragma unroll
      for (int c = 0; c < 16; ++c) ms[c] = msL[c];
#pragma unroll
      for (int u = 0; u < 6; ++u) {
        int r = tid + (u << 8);
        float pa = 0.f;
#pragma unroll
        for (int c = 0; c < 16; ++c) pa += wihL[c * 1540 + r] * ms[c];
        __hip_atomic_store(&pgb[r], pa, __ATOMIC_RELAXED, __HIP_MEMORY_SCOPE_SYSTEM);
      }
    }

    // ---- flag-array barrier (system-scope) ----
    {
      unsigned tgt = (unsigned)(kround * NN + i + 1);
      __syncthreads();   // (3)
      if (tid < 64) {
        if (tid == 0)
          __hip_atomic_store(&flags[(((b << 4) + s) << 5)], tgt, __ATOMIC_RELAXED,
                             __HIP_MEMORY_SCOPE_SYSTEM);
        unsigned* fp = &flags[(((b << 4) + (tid & 15)) << 5)];
        for (;;) {
          unsigned v = __hip_atomic_load(fp, __ATOMIC_RELAXED, __HIP_MEMORY_SCOPE_SYSTEM);
          if (!__any(v < tgt)) break;
          __builtin_amdgcn_s_sleep(1);
        }
      }
      __syncthreads();   // (4)
    }

    // ---- GRU (system-scope loads) ----
    {
      float sr0 = bi0, sr1 = bi1, sz0 = bi2, sz1 = bi3, sn0 = bi4, sn1 = bi5;
#pragma unroll
      for (int ss = 0; ss < 16; ++ss) {
        float* p = pgr + (size_t)ss * 1536;
        sr0 += __hip_atomic_load(&p[tid],        __ATOMIC_RELAXED, __HIP_MEMORY_SCOPE_SYSTEM);
        sr1 += __hip_atomic_load(&p[tid + 256],  __ATOMIC_RELAXED, __HIP_MEMORY_SCOPE_SYSTEM);
        sz0 += __hip_atomic_load(&p[512 + tid],  __ATOMIC_RELAXED, __HIP_MEMORY_SCOPE_SYSTEM);
        sz1 += __hip_atomic_load(&p[768 + tid],  __ATOMIC_RELAXED, __HIP_MEMORY_SCOPE_SYSTEM);
        sn0 += __hip_atomic_load(&p[1024 + tid], __ATOMIC_RELAXED, __HIP_MEMORY_SCOPE_SYSTEM);
        sn1 += __hip_atomic_load(&p[1280 + tid], __ATOMIC_RELAXED, __HIP_MEMORY_SCOPE_SYSTEM);
      }
      float rg0 = sigmf(sr0 + ghr0), rg1 = sigmf(sr1 + ghr1);
      float z0 = sigmf(sz0 + ghz0),  z1 = sigmf(sz1 + ghz1);
      float nv0 = tanhf_fast(sn0 + rg0 * ghn0);
      float nv1 = tanhf_fast(sn1 + rg1 * ghn1);
      float hn0 = (1.f - z0) * nv0 + z0 * hv0;
      float hn1 = (1.f - z1) * nv1 + z1 * hv1;
      hnL[tid] = hn0; hnL[tid + 256] = hn1;
      size_t rH = (size_t)(b * NN + i) * DVV;
      if ((tid >> 5) == s) h[rH + tid] = hn0;
      if (((tid + 256) >> 5) == s) h[rH + tid + 256] = hn1;
    }
    {
      int in = (i < NN - 1) ? i + 1 : NN - 1;
      size_t rH = (size_t)(b * NN + in) * DVV;
      hv0 = h[rH + tid]; hv1 = h[rH + tid + 256];
      size_t rG = (size_t)(b * NN + in) * 1536;
      ghr0 = GH[rG + tid]; ghr1 = GH[rG + tid + 256];
      ghz0 = GH[rG + 512 + tid]; ghz1 = GH[rG + 768 + tid];
      ghn0 = GH[rG + 1024 + tid]; ghn1 = GH[rG + 1280 + tid];
    }
    __syncthreads();   // (5)

    // ---- Phase C ----
    {
      int cw = tid >> 4, dg = tid & 15;
      float acc2 = 0.f;
#pragma unroll
      for (int it = 0; it < 32; ++it) {
        int d = dg + (it << 4);
        acc2 += w2L[cw * 520 + d] * hnL[d];
      }
      acc2 += __shfl_down(acc2, 8);
      acc2 += __shfl_down(acc2, 4);
      acc2 += __shfl_down(acc2, 2);
      acc2 += __shfl_down(acc2, 1);
      if (dg == 0) GL[cw * 132 + i] = acc2;
    }
  }
}

// ---------------- labels ----------------
__global__ __launch_bounds__(128) void k_labels(const float* __restrict__ h, const float* __restrict__ w_ro,
                                                const float* __restrict__ b_ro, float* __restrict__ out) {
  int b = blockIdx.x >> 7, n = blockIdx.x & 127;
  __shared__ __align__(16) float hr[512];
  int tid = threadIdx.x;
  *(float4*)&hr[tid * 4] = *(const float4*)&h[(size_t)((b << 7) + n) * DVV + tid * 4];
  __syncthreads();
  if (tid < NCC) {
    const float* w = w_ro + (size_t)tid * DVV;
    float acc = b_ro[tid];
    for (int d = 0; d < DVV; d += 4) {
      float4 wv = *(const float4*)&w[d];
      acc += wv.x * hr[d] + wv.y * hr[d + 1] + wv.z * hr[d + 2] + wv.w * hr[d + 3];
    }
    out[(size_t)((b << 7) + n) * NCC + tid] = acc;
  }
}

extern "C" void kernel_launch(void* const* d_in, const int* in_sizes, int n_in,
                              void* d_out, int out_size, void* d_ws, size_t ws_size,
                              hipStream_t stream) {
  const float* edge   = (const float*)d_in[0];
  const float* node   = (const float*)d_in[1];
  const float* w_link = (const float*)d_in[6];
  const float* b_link = (const float*)d_in[7];
  const float* w_msg  = (const float*)d_in[8];
  const float* b_msg  = (const float*)d_in[9];
  const float* w_ih   = (const float*)d_in[10];
  const float* w_hh   = (const float*)d_in[11];
  const float* b_ih   = (const float*)d_in[12];
  const float* b_hh   = (const float*)d_in[13];
  const float* w_ro   = (const float*)d_in[14];
  const float* b_ro   = (const float*)d_in[15];
  float* out = (float*)d_out;
  float* ws  = (float*)d_ws;

  float* e_buf  = ws;                      // 33,554,432  (B,N,DE,N)
  float* h_buf  = e_buf + 33554432ull;     //    524,288  (B,N,DV)
  float* GH_buf = h_buf + 524288;          //  1,572,864  (B,N,1536)
  float* U_buf  = GH_buf + 1572864;        //    262,144  (B,N,256)
  float* G_buf  = U_buf + 262144;          //    262,144  (B,N,256)
  float* lE_buf = G_buf + 262144;          //    131,072  (reused: w3b bf16 65536 ushort)
  float* av_buf = lE_buf + 131072;         //      2,048  (B,2,N)
  float* pg_buf = av_buf + 2048;           //    393,216  (2,B,16,1536)
  unsigned* flags = (unsigned*)(pg_buf + 2 * PGOFF);  // 4096 u32
  unsigned short* w3b = (unsigned short*)lE_buf;
  size_t need_bytes = 36710304ull * 4ull;
  if (ws_size < need_bytes) return;

  hipMemsetAsync(flags, 0, 4096 * sizeof(unsigned), stream);
  k_copy<<<512, 256, 0, stream>>>(node, h_buf);
  k_cvtw<<<256, 256, 0, stream>>>(w_msg, w3b);

  for (int k = 0; k < 3; ++k) {
    k_av<<<1024, 128, 0, stream>>>(h_buf, w_link, av_buf);
    if (k == 0) k_plogit_mfma<1><<<1024, 256, 0, stream>>>(edge, w3b, w_link, av_buf, b_link, e_buf, out);
    else        k_plogit_mfma<0><<<1024, 256, 0, stream>>>(e_buf, w3b, w_link, av_buf, b_link, e_buf, out);
    k_wh3<<<dim3(128, 8), 256, 0, stream>>>(w_hh, w_msg, b_hh, b_msg, h_buf, GH_buf, U_buf, G_buf);
    if (k < 2) k_scan8<1><<<dim3(SB, NB), 256, 0, stream>>>(e_buf, out, GH_buf, U_buf, G_buf, h_buf,
                                                            w_ih, b_ih, w_msg, pg_buf, flags, k);
    else       k_scan8<0><<<dim3(SB, NB), 256, 0, stream>>>(e_buf, out, GH_buf, U_buf, G_buf, h_buf,
                                                            w_ih, b_ih, w_msg, pg_buf, flags, k);
  }
  k_labels<<<1024, 128, 0, stream>>>(h_buf, w_ro, b_ro, out + 131072);
}

// Round 12
// 2310.020 us; speedup vs baseline: 2.0747x; 1.0014x over previous
//
#include <hip/hip_runtime.h>
#include <math.h>

// GPNN: B=8 graphs, N=128 nodes, DV=512, DE=256, K=3, C=117.
// R12: BISECT. R11 failed identically to R10 despite the stride fix -> the bug
// is in {k_wh3_mfma} or {e-bf16 path}. This round: k_wh3_mfma reverted to R9's
// proven scalar k_wh3 (fp32 h_buf); e-bf16 path (plogit bf16 + scan bf16 P)
// kept. PASS => wh3_mfma guilty. FAIL => e-bf16 guilty.

#define NB 8
#define NN 128
#define DVV 512
#define DEE 256
#define NCC 117
#define SB 16
#define PGOFF 196608   // floats per pg parity buffer (8*16*1536)

typedef __attribute__((ext_vector_type(8))) short short8;
typedef __attribute__((ext_vector_type(4))) float f32x4;

__device__ __forceinline__ float sigmf(float x) {
  x = fminf(fmaxf(x, -30.f), 30.f);
  return 1.0f / (1.0f + __expf(-x));
}
__device__ __forceinline__ float tanhf_fast(float x) {
  x = fminf(fmaxf(x, -15.f), 15.f);
  float e = __expf(2.0f * x);
  return (e - 1.0f) / (e + 1.0f);
}
__device__ __forceinline__ unsigned short f2bf(float f) {
  union { float f; unsigned u; } v; v.f = f;
  unsigned u = v.u + 0x7FFFu + ((v.u >> 16) & 1u);
  return (unsigned short)(u >> 16);
}
__device__ __forceinline__ float bfu(unsigned short u) {
  union { unsigned u; float f; } v; v.u = ((unsigned)u) << 16; return v.f;
}

// ---------------- h init (+ hb bf16, kept for future wh3_mfma retry) ----------------
__global__ __launch_bounds__(256) void k_copy(const float* __restrict__ src, float* __restrict__ dst,
                                              unsigned short* __restrict__ hb) {
  int i = blockIdx.x * 256 + threadIdx.x;
  float4 v = ((const float4*)src)[i];
  ((float4*)dst)[i] = v;
  unsigned long long pk = (unsigned long long)f2bf(v.x) | ((unsigned long long)f2bf(v.y) << 16)
                        | ((unsigned long long)f2bf(v.z) << 32) | ((unsigned long long)f2bf(v.w) << 48);
  *(unsigned long long*)&hb[i * 4] = pk;
}

// ---------------- W3 -> bf16 (once) ----------------
__global__ __launch_bounds__(256) void k_cvtw(const float* __restrict__ w_msg,
                                              unsigned short* __restrict__ w3b) {
  int idx = blockIdx.x * 256 + threadIdx.x;      // 65536
  int r = idx >> 8, c = idx & 255;
  w3b[idx] = f2bf(w_msg[(size_t)r * 1280 + 1024 + c]);
}

// ---------------- ai/aj ----------------
__global__ __launch_bounds__(128) void k_av(const float* __restrict__ h, const float* __restrict__ w_link,
                                            float* __restrict__ av) {
  int b = blockIdx.x >> 7, n = blockIdx.x & 127;
  int lane = threadIdx.x & 63, half = threadIdx.x >> 6;
  const float* hc = h + (size_t)((b << 7) + n) * DVV;
  const float* w = w_link + half * DVV;
  float acc = 0.f;
#pragma unroll
  for (int t = 0; t < 8; ++t) { int d = lane + (t << 6); acc += w[d] * hc[d]; }
#pragma unroll
  for (int off = 32; off; off >>= 1) acc += __shfl_down(acc, off);
  if (lane == 0) av[(b << 8) + half * NN + n] = acc;
}

// ---------------- per-row: adj (fused) + P = W3 @ e_row via bf16 MFMA; e bf16 [c][j] ----------------
template <int FIRST>
__global__ __launch_bounds__(256) void k_plogit_mfma(
    const float* edge, const unsigned short* eP16in, const unsigned short* __restrict__ w3b,
    const float* __restrict__ w_link, const float* __restrict__ av,
    const float* __restrict__ b_link, unsigned short* eP16out, float* __restrict__ adj_out) {
  int b = blockIdx.x >> 7, i = blockIdx.x & 127;
  __shared__ unsigned short eL[128 * 264];       // [j][c], 528B rows (16B-aligned)
  int tid = threadIdx.x;

  if (FIRST) {
    const float* s0 = edge + (size_t)(b * NN + i) * NN * DEE;
    for (int l = tid; l < 4096; l += 256) {
      int j = l >> 5, c0 = (l & 31) * 8;
      float4 v0 = *(const float4*)&s0[(size_t)j * DEE + c0];
      float4 v1 = *(const float4*)&s0[(size_t)j * DEE + c0 + 4];
      unsigned long long p0 = (unsigned long long)f2bf(v0.x) | ((unsigned long long)f2bf(v0.y) << 16)
                            | ((unsigned long long)f2bf(v0.z) << 32) | ((unsigned long long)f2bf(v0.w) << 48);
      unsigned long long p1 = (unsigned long long)f2bf(v1.x) | ((unsigned long long)f2bf(v1.y) << 16)
                            | ((unsigned long long)f2bf(v1.z) << 32) | ((unsigned long long)f2bf(v1.w) << 48);
      *(unsigned long long*)&eL[j * 264 + c0] = p0;
      *(unsigned long long*)&eL[j * 264 + c0 + 4] = p1;
    }
  } else {
    const unsigned short* s0 = eP16in + (size_t)(b * NN + i) * DEE * NN;
#pragma unroll
    for (int t = 0; t < 2; ++t) {
      int blk = tid + t * 256;                   // 512 8x8 blocks
      int c0 = (blk >> 4) * 8, j0 = (blk & 15) * 8;
      short8 rows[8];
#pragma unroll
      for (int cc = 0; cc < 8; ++cc)
        rows[cc] = *(const short8*)&s0[(size_t)(c0 + cc) * NN + j0];
#pragma unroll
      for (int jj = 0; jj < 8; ++jj) {
        short8 o;
#pragma unroll
        for (int cc = 0; cc < 8; ++cc) o[cc] = rows[cc][jj];
        *(short8*)&eL[(j0 + jj) * 264 + c0] = o;
      }
    }
  }
  __syncthreads();

  // logitE per j
  float accLE = 0.f;
  if (tid < NN) {
    const unsigned short* row = &eL[tid * 264];
    for (int c = 0; c < DEE; ++c) accLE += w_link[1024 + c] * bfu(row[c]);
  }

  // MFMA main loop
  const int w = tid >> 6, l = tid & 63;
  const int lm = l & 15, lg = l >> 4;
  f32x4 acc[4][8];
#pragma unroll
  for (int a = 0; a < 4; ++a)
#pragma unroll
    for (int jt = 0; jt < 8; ++jt) acc[a][jt] = (f32x4){0.f, 0.f, 0.f, 0.f};

#pragma unroll
  for (int kk = 0; kk < 8; ++kk) {
    short8 afr[4];
#pragma unroll
    for (int a = 0; a < 4; ++a)
      afr[a] = *(const short8*)&w3b[(size_t)(64 * w + 16 * a + lm) * 256 + 32 * kk + 8 * lg];
#pragma unroll
    for (int jt = 0; jt < 8; ++jt) {
      short8 bfr = *(const short8*)&eL[(16 * jt + lm) * 264 + 32 * kk + 8 * lg];
#pragma unroll
      for (int a = 0; a < 4; ++a)
        acc[a][jt] = __builtin_amdgcn_mfma_f32_16x16x32_bf16(afr[a], bfr, acc[a][jt], 0, 0, 0);
    }
  }

  // epilogue: P bf16 [c][j]
  unsigned short* Pout = eP16out + (size_t)(b * NN + i) * DEE * NN;
#pragma unroll
  for (int a = 0; a < 4; ++a) {
    int rbase = 64 * w + 16 * a + 4 * lg;
#pragma unroll
    for (int jt = 0; jt < 8; ++jt) {
      int j = 16 * jt + lm;
#pragma unroll
      for (int q = 0; q < 4; ++q)
        Pout[(size_t)(rbase + q) * NN + j] = f2bf(acc[a][jt][q]);
    }
  }
  if (tid < NN) {
    float x = av[(b << 8) + NN + i] + av[(b << 8) + tid] + accLE + b_link[0];
    adj_out[((size_t)b * NN + i) * NN + tid] = sigmf(x);
  }
}

// ---------------- merged W@h kernel (R9 scalar, PROVEN): GH (96 blk) + U (16) + G (16) ----------------
__global__ __launch_bounds__(256) void k_wh3(const float* __restrict__ w_hh, const float* __restrict__ w_msg,
                                             const float* __restrict__ b_hh, const float* __restrict__ b_msg,
                                             const float* __restrict__ h, float* __restrict__ GHo,
                                             float* __restrict__ Uo, float* __restrict__ Go) {
  int bx = blockIdx.x, b = blockIdx.y;
  const float* W; const float* bias; float* out; int ldw, R, r0;
  if (bx < 96)       { W = w_hh;        ldw = 512;  R = 1536; bias = b_hh;   out = GHo; r0 = bx * 16; }
  else if (bx < 112) { W = w_msg;       ldw = 1280; R = 256;  bias = b_msg;  out = Uo;  r0 = (bx - 96) * 16; }
  else               { W = w_msg + 512; ldw = 1280; R = 256;  bias = nullptr; out = Go; r0 = (bx - 112) * 16; }
  __shared__ float hT[128][129];
  __shared__ float wT[16][129];
  __shared__ float outT[16][129];
  int tid = threadIdx.x;
  int n = tid & 127, rr = tid >> 7;
  float acc8[8] = {0, 0, 0, 0, 0, 0, 0, 0};
  for (int dc = 0; dc < DVV; dc += 128) {
    if (dc) __syncthreads();
    for (int l = tid * 4; l < 16384; l += 1024) {
      int nn = l >> 7, d = l & 127;
      float4 v = *(const float4*)&h[((size_t)(b << 7) + nn) * DVV + dc + d];
      hT[d + 0][nn] = v.x; hT[d + 1][nn] = v.y; hT[d + 2][nn] = v.z; hT[d + 3][nn] = v.w;
    }
    for (int l = tid; l < 2048; l += 256) {
      int r = l >> 7, d = l & 127;
      wT[r][d] = W[(size_t)(r0 + r) * ldw + dc + d];
    }
    __syncthreads();
    for (int d = 0; d < 128; ++d) {
      float hval = hT[d][n];
#pragma unroll
      for (int r8 = 0; r8 < 8; ++r8) acc8[r8] += wT[rr * 8 + r8][d] * hval;
    }
  }
#pragma unroll
  for (int r8 = 0; r8 < 8; ++r8) {
    int r = rr * 8 + r8;
    outT[r][n] = acc8[r8] + (bias ? bias[r0 + r] : 0.0f);
  }
  __syncthreads();
  int n2 = tid >> 1, q = tid & 1;
  size_t base = ((size_t)(b << 7) + n2) * R + r0 + q * 8;
  float4 o0; o0.x = outT[q * 8 + 0][n2]; o0.y = outT[q * 8 + 1][n2]; o0.z = outT[q * 8 + 2][n2]; o0.w = outT[q * 8 + 3][n2];
  float4 o1; o1.x = outT[q * 8 + 4][n2]; o1.y = outT[q * 8 + 5][n2]; o1.z = outT[q * 8 + 6][n2]; o1.w = outT[q * 8 + 7][n2];
  *(float4*)&out[base] = o0;
  *(float4*)&out[base + 4] = o1;
}

// ---------------- distributed scan (R8 protocol; eP bf16) ----------------
template <int WRITE_E>
__global__ __launch_bounds__(256) void k_scan10(
    unsigned short* eP16, const float* __restrict__ adj, const float* __restrict__ GH,
    const float* __restrict__ U, const float* __restrict__ Gini, float* __restrict__ h,
    unsigned short* __restrict__ hb, const float* __restrict__ w_ih,
    const float* __restrict__ b_ih, const float* __restrict__ w_msg,
    float* __restrict__ pg, unsigned* __restrict__ flags, int kround) {
  const int s = blockIdx.x, b = blockIdx.y, tid = threadIdx.x;
  __shared__ float wihL[16 * 1540];
  __shared__ __align__(16) float w2L[16 * 520];
  __shared__ __align__(16) float GL[16 * 132];
  __shared__ float hnL[DVV];
  __shared__ float msL[16];

  for (int l = tid; l < 1536 * 16; l += 256) {
    int r = l >> 4, c = l & 15;
    wihL[c * 1540 + r] = w_ih[(size_t)r * 256 + 16 * s + c];
  }
  for (int l = tid; l < 16 * 128; l += 256) {
    int c = l >> 7, d4 = (l & 127) * 4;
    *(float4*)&w2L[c * 520 + d4] = *(const float4*)&w_msg[(size_t)(16 * s + c) * 1280 + 512 + d4];
  }
  for (int l = tid; l < 2048; l += 256) {
    int c = l & 15, j = l >> 4;
    GL[c * 132 + j] = Gini[((size_t)b * NN + j) * DEE + 16 * s + c];
  }
  float bi0 = b_ih[tid], bi1 = b_ih[tid + 256];
  float bi2 = b_ih[512 + tid], bi3 = b_ih[768 + tid];
  float bi4 = b_ih[1024 + tid], bi5 = b_ih[1280 + tid];

  const int c_loc = tid >> 4, jg = tid & 15, j0 = jg << 3;

  short8 Pv; float4 A0, A1; float uu;
  float hv0, hv1, ghr0, ghr1, ghz0, ghz1, ghn0, ghn1;
  {
    size_t rE = ((size_t)(b * NN + 0) * DEE + 16 * s + c_loc) * NN + j0;
    Pv = *(const short8*)&eP16[rE];
    size_t rA = (size_t)(b * NN + 0) * NN + j0;
    A0 = *(const float4*)&adj[rA]; A1 = *(const float4*)&adj[rA + 4];
    uu = U[(size_t)(b * NN + 0) * DEE + 16 * s + c_loc];
    size_t rH = (size_t)(b * NN + 0) * DVV;
    hv0 = h[rH + tid]; hv1 = h[rH + tid + 256];
    size_t rG = (size_t)(b * NN + 0) * 1536;
    ghr0 = GH[rG + tid]; ghr1 = GH[rG + tid + 256];
    ghz0 = GH[rG + 512 + tid]; ghz1 = GH[rG + 768 + tid];
    ghn0 = GH[rG + 1024 + tid]; ghn1 = GH[rG + 1280 + tid];
  }

  for (int i = 0; i < NN; ++i) {
    float* pgb = pg + (size_t)(i & 1) * PGOFF + (size_t)((b << 4) + s) * 1536;
    float* pgr = pg + (size_t)(i & 1) * PGOFF + (size_t)(b << 4) * 1536;
    __syncthreads();   // (1)

    // ---- Phase A ----
    float acc;
    {
      const float* gl = &GL[c_loc * 132 + j0];
      float4 g0 = *(const float4*)&gl[0];
      float4 g1 = *(const float4*)&gl[4];
      float m0 = fmaxf(uu + g0.x + bfu((unsigned short)Pv[0]), 0.f);
      float m1 = fmaxf(uu + g0.y + bfu((unsigned short)Pv[1]), 0.f);
      float m2 = fmaxf(uu + g0.z + bfu((unsigned short)Pv[2]), 0.f);
      float m3 = fmaxf(uu + g0.w + bfu((unsigned short)Pv[3]), 0.f);
      float m4 = fmaxf(uu + g1.x + bfu((unsigned short)Pv[4]), 0.f);
      float m5 = fmaxf(uu + g1.y + bfu((unsigned short)Pv[5]), 0.f);
      float m6 = fmaxf(uu + g1.z + bfu((unsigned short)Pv[6]), 0.f);
      float m7 = fmaxf(uu + g1.w + bfu((unsigned short)Pv[7]), 0.f);
      acc = A0.x * m0 + A0.y * m1 + A0.z * m2 + A0.w * m3
          + A1.x * m4 + A1.y * m5 + A1.z * m6 + A1.w * m7;
      if (WRITE_E) {
        size_t rE = ((size_t)(b * NN + i) * DEE + 16 * s + c_loc) * NN + j0;
        short8 mw;
        mw[0] = (short)f2bf(m0); mw[1] = (short)f2bf(m1); mw[2] = (short)f2bf(m2); mw[3] = (short)f2bf(m3);
        mw[4] = (short)f2bf(m4); mw[5] = (short)f2bf(m5); mw[6] = (short)f2bf(m6); mw[7] = (short)f2bf(m7);
        *(short8*)&eP16[rE] = mw;
      }
    }
    {
      int in = (i < NN - 1) ? i + 1 : NN - 1;
      size_t rE = ((size_t)(b * NN + in) * DEE + 16 * s + c_loc) * NN + j0;
      Pv = *(const short8*)&eP16[rE];
      size_t rA = (size_t)(b * NN + in) * NN + j0;
      A0 = *(const float4*)&adj[rA]; A1 = *(const float4*)&adj[rA + 4];
      uu = U[(size_t)(b * NN + in) * DEE + 16 * s + c_loc];
    }
    acc += __shfl_down(acc, 8);
    acc += __shfl_down(acc, 4);
    acc += __shfl_down(acc, 2);
    acc += __shfl_down(acc, 1);
    if (jg == 0) msL[c_loc] = acc;
    __syncthreads();   // (2)

    // ---- Phase B (system-scope stores) ----
    {
      float ms[16];
#pragma unroll
      for (int c = 0; c < 16; ++c) ms[c] = msL[c];
#pragma unroll
      for (int u = 0; u < 6; ++u) {
        int r = tid + (u << 8);
        float pa = 0.f;
#pragma unroll
        for (int c = 0; c < 16; ++c) pa += wihL[c * 1540 + r] * ms[c];
        __hip_atomic_store(&pgb[r], pa, __ATOMIC_RELAXED, __HIP_MEMORY_SCOPE_SYSTEM);
      }
    }

    // ---- flag-array barrier (system-scope) ----
    {
      unsigned tgt = (unsigned)(kround * NN + i + 1);
      __syncthreads();   // (3)
      if (tid < 64) {
        if (tid == 0)
          __hip_atomic_store(&flags[(((b << 4) + s) << 5)], tgt, __ATOMIC_RELAXED,
                             __HIP_MEMORY_SCOPE_SYSTEM);
        unsigned* fp = &flags[(((b << 4) + (tid & 15)) << 5)];
        for (;;) {
          unsigned v = __hip_atomic_load(fp, __ATOMIC_RELAXED, __HIP_MEMORY_SCOPE_SYSTEM);
          if (!__any(v < tgt)) break;
          __builtin_amdgcn_s_sleep(1);
        }
      }
      __syncthreads();   // (4)
    }

    // ---- GRU (system-scope loads) ----
    {
      float sr0 = bi0, sr1 = bi1, sz0 = bi2, sz1 = bi3, sn0 = bi4, sn1 = bi5;
#pragma unroll
      for (int ss = 0; ss < 16; ++ss) {
        float* p = pgr + (size_t)ss * 1536;
        sr0 += __hip_atomic_load(&p[tid],        __ATOMIC_RELAXED, __HIP_MEMORY_SCOPE_SYSTEM);
        sr1 += __hip_atomic_load(&p[tid + 256],  __ATOMIC_RELAXED, __HIP_MEMORY_SCOPE_SYSTEM);
        sz0 += __hip_atomic_load(&p[512 + tid],  __ATOMIC_RELAXED, __HIP_MEMORY_SCOPE_SYSTEM);
        sz1 += __hip_atomic_load(&p[768 + tid],  __ATOMIC_RELAXED, __HIP_MEMORY_SCOPE_SYSTEM);
        sn0 += __hip_atomic_load(&p[1024 + tid], __ATOMIC_RELAXED, __HIP_MEMORY_SCOPE_SYSTEM);
        sn1 += __hip_atomic_load(&p[1280 + tid], __ATOMIC_RELAXED, __HIP_MEMORY_SCOPE_SYSTEM);
      }
      float rg0 = sigmf(sr0 + ghr0), rg1 = sigmf(sr1 + ghr1);
      float z0 = sigmf(sz0 + ghz0),  z1 = sigmf(sz1 + ghz1);
      float nv0 = tanhf_fast(sn0 + rg0 * ghn0);
      float nv1 = tanhf_fast(sn1 + rg1 * ghn1);
      float hn0 = (1.f - z0) * nv0 + z0 * hv0;
      float hn1 = (1.f - z1) * nv1 + z1 * hv1;
      hnL[tid] = hn0; hnL[tid + 256] = hn1;
      size_t rH = (size_t)(b * NN + i) * DVV;
      if ((tid >> 5) == s)         { h[rH + tid] = hn0;       hb[rH + tid] = f2bf(hn0); }
      if (((tid + 256) >> 5) == s) { h[rH + tid + 256] = hn1; hb[rH + tid + 256] = f2bf(hn1); }
    }
    {
      int in = (i < NN - 1) ? i + 1 : NN - 1;
      size_t rH = (size_t)(b * NN + in) * DVV;
      hv0 = h[rH + tid]; hv1 = h[rH + tid + 256];
      size_t rG = (size_t)(b * NN + in) * 1536;
      ghr0 = GH[rG + tid]; ghr1 = GH[rG + tid + 256];
      ghz0 = GH[rG + 512 + tid]; ghz1 = GH[rG + 768 + tid];
      ghn0 = GH[rG + 1024 + tid]; ghn1 = GH[rG + 1280 + tid];
    }
    __syncthreads();   // (5)

    // ---- Phase C ----
    {
      int cw = tid >> 4, dg = tid & 15;
      float acc2 = 0.f;
#pragma unroll
      for (int it = 0; it < 32; ++it) {
        int d = dg + (it << 4);
        acc2 += w2L[cw * 520 + d] * hnL[d];
      }
      acc2 += __shfl_down(acc2, 8);
      acc2 += __shfl_down(acc2, 4);
      acc2 += __shfl_down(acc2, 2);
      acc2 += __shfl_down(acc2, 1);
      if (dg == 0) GL[cw * 132 + i] = acc2;
    }
  }
}

// ---------------- labels ----------------
__global__ __launch_bounds__(128) void k_labels(const float* __restrict__ h, const float* __restrict__ w_ro,
                                                const float* __restrict__ b_ro, float* __restrict__ out) {
  int b = blockIdx.x >> 7, n = blockIdx.x & 127;
  __shared__ __align__(16) float hr[512];
  int tid = threadIdx.x;
  *(float4*)&hr[tid * 4] = *(const float4*)&h[(size_t)((b << 7) + n) * DVV + tid * 4];
  __syncthreads();
  if (tid < NCC) {
    const float* w = w_ro + (size_t)tid * DVV;
    float acc = b_ro[tid];
    for (int d = 0; d < DVV; d += 4) {
      float4 wv = *(const float4*)&w[d];
      acc += wv.x * hr[d] + wv.y * hr[d + 1] + wv.z * hr[d + 2] + wv.w * hr[d + 3];
    }
    out[(size_t)((b << 7) + n) * NCC + tid] = acc;
  }
}

extern "C" void kernel_launch(void* const* d_in, const int* in_sizes, int n_in,
                              void* d_out, int out_size, void* d_ws, size_t ws_size,
                              hipStream_t stream) {
  const float* edge   = (const float*)d_in[0];
  const float* node   = (const float*)d_in[1];
  const float* w_link = (const float*)d_in[6];
  const float* b_link = (const float*)d_in[7];
  const float* w_msg  = (const float*)d_in[8];
  const float* b_msg  = (const float*)d_in[9];
  const float* w_ih   = (const float*)d_in[10];
  const float* w_hh   = (const float*)d_in[11];
  const float* b_ih   = (const float*)d_in[12];
  const float* b_hh   = (const float*)d_in[13];
  const float* w_ro   = (const float*)d_in[14];
  const float* b_ro   = (const float*)d_in[15];
  float* out = (float*)d_out;
  float* ws  = (float*)d_ws;

  unsigned short* eP16 = (unsigned short*)ws;               // 33,554,432 ushorts (16.78M floats)
  unsigned short* hb   = (unsigned short*)(ws + 21000000);  //   524,288 ushorts
  float* h_buf  = ws + 33554432ull;        //    524,288  (B,N,DV)
  float* GH_buf = h_buf + 524288;          //  1,572,864  (B,N,1536)
  float* U_buf  = GH_buf + 1572864;        //    262,144  (B,N,256)
  float* G_buf  = U_buf + 262144;          //    262,144  (B,N,256)
  float* lE_buf = G_buf + 262144;          //    131,072  (reused: w3b)
  float* av_buf = lE_buf + 131072;         //      2,048  (B,2,N)
  float* pg_buf = av_buf + 2048;           //    393,216  (2,B,16,1536)
  unsigned* flags = (unsigned*)(pg_buf + 2 * PGOFF);  // 4096 u32
  unsigned short* w3b = (unsigned short*)lE_buf;
  size_t need_bytes = 36710304ull * 4ull;
  if (ws_size < need_bytes) return;

  hipMemsetAsync(flags, 0, 4096 * sizeof(unsigned), stream);
  k_copy<<<512, 256, 0, stream>>>(node, h_buf, hb);
  k_cvtw<<<256, 256, 0, stream>>>(w_msg, w3b);

  for (int k = 0; k < 3; ++k) {
    k_av<<<1024, 128, 0, stream>>>(h_buf, w_link, av_buf);
    if (k == 0) k_plogit_mfma<1><<<1024, 256, 0, stream>>>(edge, eP16, w3b, w_link, av_buf, b_link, eP16, out);
    else        k_plogit_mfma<0><<<1024, 256, 0, stream>>>(edge, eP16, w3b, w_link, av_buf, b_link, eP16, out);
    k_wh3<<<dim3(128, 8), 256, 0, stream>>>(w_hh, w_msg, b_hh, b_msg, h_buf, GH_buf, U_buf, G_buf);
    if (k < 2) k_scan10<1><<<dim3(SB, NB), 256, 0, stream>>>(eP16, out, GH_buf, U_buf, G_buf, h_buf, hb,
                                                             w_ih, b_ih, w_msg, pg_buf, flags, k);
    else       k_scan10<0><<<dim3(SB, NB), 256, 0, stream>>>(eP16, out, GH_buf, U_buf, G_buf, h_buf, hb,
                                                             w_ih, b_ih, w_msg, pg_buf, flags, k);
  }
  k_labels<<<1024, 128, 0, stream>>>(h_buf, w_ro, b_ro, out + 131072);
}

// Round 13
// 1952.822 us; speedup vs baseline: 2.4542x; 1.1829x over previous
//
#include <hip/hip_runtime.h>
#include <math.h>

// GPNN: B=8 graphs, N=128 nodes, DV=512, DE=256, K=3, C=117.
// R13: scan GRU exchange via L3 atomicAdd accumulator (gi[b][1536], mod-3 slot
// rotation for zero-init; race-freedom by barrier ordering). GRU partial reads
// drop 90 -> 6 loads/thread. Everything else = R12 (proven).

#define NB 8
#define NN 128
#define DVV 512
#define DEE 256
#define NCC 117
#define SB 16
#define GISLOT 12288   // floats per gi slot (8 batches x 1536)

typedef __attribute__((ext_vector_type(8))) short short8;
typedef __attribute__((ext_vector_type(4))) float f32x4;

__device__ __forceinline__ float sigmf(float x) {
  x = fminf(fmaxf(x, -30.f), 30.f);
  return 1.0f / (1.0f + __expf(-x));
}
__device__ __forceinline__ float tanhf_fast(float x) {
  x = fminf(fmaxf(x, -15.f), 15.f);
  float e = __expf(2.0f * x);
  return (e - 1.0f) / (e + 1.0f);
}
__device__ __forceinline__ unsigned short f2bf(float f) {
  union { float f; unsigned u; } v; v.f = f;
  unsigned u = v.u + 0x7FFFu + ((v.u >> 16) & 1u);
  return (unsigned short)(u >> 16);
}
__device__ __forceinline__ float bfu(unsigned short u) {
  union { unsigned u; float f; } v; v.u = ((unsigned)u) << 16; return v.f;
}

// ---------------- h init (+ hb bf16) ----------------
__global__ __launch_bounds__(256) void k_copy(const float* __restrict__ src, float* __restrict__ dst,
                                              unsigned short* __restrict__ hb) {
  int i = blockIdx.x * 256 + threadIdx.x;
  float4 v = ((const float4*)src)[i];
  ((float4*)dst)[i] = v;
  unsigned long long pk = (unsigned long long)f2bf(v.x) | ((unsigned long long)f2bf(v.y) << 16)
                        | ((unsigned long long)f2bf(v.z) << 32) | ((unsigned long long)f2bf(v.w) << 48);
  *(unsigned long long*)&hb[i * 4] = pk;
}

// ---------------- W3 -> bf16 (once) ----------------
__global__ __launch_bounds__(256) void k_cvtw(const float* __restrict__ w_msg,
                                              unsigned short* __restrict__ w3b) {
  int idx = blockIdx.x * 256 + threadIdx.x;      // 65536
  int r = idx >> 8, c = idx & 255;
  w3b[idx] = f2bf(w_msg[(size_t)r * 1280 + 1024 + c]);
}

// ---------------- ai/aj ----------------
__global__ __launch_bounds__(128) void k_av(const float* __restrict__ h, const float* __restrict__ w_link,
                                            float* __restrict__ av) {
  int b = blockIdx.x >> 7, n = blockIdx.x & 127;
  int lane = threadIdx.x & 63, half = threadIdx.x >> 6;
  const float* hc = h + (size_t)((b << 7) + n) * DVV;
  const float* w = w_link + half * DVV;
  float acc = 0.f;
#pragma unroll
  for (int t = 0; t < 8; ++t) { int d = lane + (t << 6); acc += w[d] * hc[d]; }
#pragma unroll
  for (int off = 32; off; off >>= 1) acc += __shfl_down(acc, off);
  if (lane == 0) av[(b << 8) + half * NN + n] = acc;
}

// ---------------- per-row: adj (fused) + P = W3 @ e_row via bf16 MFMA; e bf16 [c][j] ----------------
template <int FIRST>
__global__ __launch_bounds__(256) void k_plogit_mfma(
    const float* edge, const unsigned short* eP16in, const unsigned short* __restrict__ w3b,
    const float* __restrict__ w_link, const float* __restrict__ av,
    const float* __restrict__ b_link, unsigned short* eP16out, float* __restrict__ adj_out) {
  int b = blockIdx.x >> 7, i = blockIdx.x & 127;
  __shared__ unsigned short eL[128 * 264];       // [j][c], 528B rows (16B-aligned)
  int tid = threadIdx.x;

  if (FIRST) {
    const float* s0 = edge + (size_t)(b * NN + i) * NN * DEE;
    for (int l = tid; l < 4096; l += 256) {
      int j = l >> 5, c0 = (l & 31) * 8;
      float4 v0 = *(const float4*)&s0[(size_t)j * DEE + c0];
      float4 v1 = *(const float4*)&s0[(size_t)j * DEE + c0 + 4];
      unsigned long long p0 = (unsigned long long)f2bf(v0.x) | ((unsigned long long)f2bf(v0.y) << 16)
                            | ((unsigned long long)f2bf(v0.z) << 32) | ((unsigned long long)f2bf(v0.w) << 48);
      unsigned long long p1 = (unsigned long long)f2bf(v1.x) | ((unsigned long long)f2bf(v1.y) << 16)
                            | ((unsigned long long)f2bf(v1.z) << 32) | ((unsigned long long)f2bf(v1.w) << 48);
      *(unsigned long long*)&eL[j * 264 + c0] = p0;
      *(unsigned long long*)&eL[j * 264 + c0 + 4] = p1;
    }
  } else {
    const unsigned short* s0 = eP16in + (size_t)(b * NN + i) * DEE * NN;
#pragma unroll
    for (int t = 0; t < 2; ++t) {
      int blk = tid + t * 256;                   // 512 8x8 blocks
      int c0 = (blk >> 4) * 8, j0 = (blk & 15) * 8;
      short8 rows[8];
#pragma unroll
      for (int cc = 0; cc < 8; ++cc)
        rows[cc] = *(const short8*)&s0[(size_t)(c0 + cc) * NN + j0];
#pragma unroll
      for (int jj = 0; jj < 8; ++jj) {
        short8 o;
#pragma unroll
        for (int cc = 0; cc < 8; ++cc) o[cc] = rows[cc][jj];
        *(short8*)&eL[(j0 + jj) * 264 + c0] = o;
      }
    }
  }
  __syncthreads();

  // logitE per j
  float accLE = 0.f;
  if (tid < NN) {
    const unsigned short* row = &eL[tid * 264];
    for (int c = 0; c < DEE; ++c) accLE += w_link[1024 + c] * bfu(row[c]);
  }

  // MFMA main loop
  const int w = tid >> 6, l = tid & 63;
  const int lm = l & 15, lg = l >> 4;
  f32x4 acc[4][8];
#pragma unroll
  for (int a = 0; a < 4; ++a)
#pragma unroll
    for (int jt = 0; jt < 8; ++jt) acc[a][jt] = (f32x4){0.f, 0.f, 0.f, 0.f};

#pragma unroll
  for (int kk = 0; kk < 8; ++kk) {
    short8 afr[4];
#pragma unroll
    for (int a = 0; a < 4; ++a)
      afr[a] = *(const short8*)&w3b[(size_t)(64 * w + 16 * a + lm) * 256 + 32 * kk + 8 * lg];
#pragma unroll
    for (int jt = 0; jt < 8; ++jt) {
      short8 bfr = *(const short8*)&eL[(16 * jt + lm) * 264 + 32 * kk + 8 * lg];
#pragma unroll
      for (int a = 0; a < 4; ++a)
        acc[a][jt] = __builtin_amdgcn_mfma_f32_16x16x32_bf16(afr[a], bfr, acc[a][jt], 0, 0, 0);
    }
  }

  // epilogue: P bf16 [c][j]
  unsigned short* Pout = eP16out + (size_t)(b * NN + i) * DEE * NN;
#pragma unroll
  for (int a = 0; a < 4; ++a) {
    int rbase = 64 * w + 16 * a + 4 * lg;
#pragma unroll
    for (int jt = 0; jt < 8; ++jt) {
      int j = 16 * jt + lm;
#pragma unroll
      for (int q = 0; q < 4; ++q)
        Pout[(size_t)(rbase + q) * NN + j] = f2bf(acc[a][jt][q]);
    }
  }
  if (tid < NN) {
    float x = av[(b << 8) + NN + i] + av[(b << 8) + tid] + accLE + b_link[0];
    adj_out[((size_t)b * NN + i) * NN + tid] = sigmf(x);
  }
}

// ---------------- merged W@h kernel (R9 scalar, PROVEN) ----------------
__global__ __launch_bounds__(256) void k_wh3(const float* __restrict__ w_hh, const float* __restrict__ w_msg,
                                             const float* __restrict__ b_hh, const float* __restrict__ b_msg,
                                             const float* __restrict__ h, float* __restrict__ GHo,
                                             float* __restrict__ Uo, float* __restrict__ Go) {
  int bx = blockIdx.x, b = blockIdx.y;
  const float* W; const float* bias; float* out; int ldw, R, r0;
  if (bx < 96)       { W = w_hh;        ldw = 512;  R = 1536; bias = b_hh;   out = GHo; r0 = bx * 16; }
  else if (bx < 112) { W = w_msg;       ldw = 1280; R = 256;  bias = b_msg;  out = Uo;  r0 = (bx - 96) * 16; }
  else               { W = w_msg + 512; ldw = 1280; R = 256;  bias = nullptr; out = Go; r0 = (bx - 112) * 16; }
  __shared__ float hT[128][129];
  __shared__ float wT[16][129];
  __shared__ float outT[16][129];
  int tid = threadIdx.x;
  int n = tid & 127, rr = tid >> 7;
  float acc8[8] = {0, 0, 0, 0, 0, 0, 0, 0};
  for (int dc = 0; dc < DVV; dc += 128) {
    if (dc) __syncthreads();
    for (int l = tid * 4; l < 16384; l += 1024) {
      int nn = l >> 7, d = l & 127;
      float4 v = *(const float4*)&h[((size_t)(b << 7) + nn) * DVV + dc + d];
      hT[d + 0][nn] = v.x; hT[d + 1][nn] = v.y; hT[d + 2][nn] = v.z; hT[d + 3][nn] = v.w;
    }
    for (int l = tid; l < 2048; l += 256) {
      int r = l >> 7, d = l & 127;
      wT[r][d] = W[(size_t)(r0 + r) * ldw + dc + d];
    }
    __syncthreads();
    for (int d = 0; d < 128; ++d) {
      float hval = hT[d][n];
#pragma unroll
      for (int r8 = 0; r8 < 8; ++r8) acc8[r8] += wT[rr * 8 + r8][d] * hval;
    }
  }
#pragma unroll
  for (int r8 = 0; r8 < 8; ++r8) {
    int r = rr * 8 + r8;
    outT[r][n] = acc8[r8] + (bias ? bias[r0 + r] : 0.0f);
  }
  __syncthreads();
  int n2 = tid >> 1, q = tid & 1;
  size_t base = ((size_t)(b << 7) + n2) * R + r0 + q * 8;
  float4 o0; o0.x = outT[q * 8 + 0][n2]; o0.y = outT[q * 8 + 1][n2]; o0.z = outT[q * 8 + 2][n2]; o0.w = outT[q * 8 + 3][n2];
  float4 o1; o1.x = outT[q * 8 + 4][n2]; o1.y = outT[q * 8 + 5][n2]; o1.z = outT[q * 8 + 6][n2]; o1.w = outT[q * 8 + 7][n2];
  *(float4*)&out[base] = o0;
  *(float4*)&out[base + 4] = o1;
}

// ---------------- distributed scan: gi = L3 atomicAdd accumulator, mod-3 slots ----------------
// Step g = kround*NN + i: phase B atomicAdds partials into slot g%3 and zeroes
// slot (g+1)%3. Zero drains at sync(3) before flag(g) => precedes step-(g+1)
// adds. Slot (g+1)%3's last reads (GRU g-2) finished before barrier(g-1),
// which this block passed. GRU reads slot g%3: 6 sc1 loads/thread.
template <int WRITE_E>
__global__ __launch_bounds__(256) void k_scan13(
    unsigned short* eP16, const float* __restrict__ adj, const float* __restrict__ GH,
    const float* __restrict__ U, const float* __restrict__ Gini, float* __restrict__ h,
    unsigned short* __restrict__ hb, const float* __restrict__ w_ih,
    const float* __restrict__ b_ih, const float* __restrict__ w_msg,
    float* __restrict__ gi, unsigned* __restrict__ flags, int kround) {
  const int s = blockIdx.x, b = blockIdx.y, tid = threadIdx.x;
  __shared__ float wihL[16 * 1540];
  __shared__ __align__(16) float w2L[16 * 520];
  __shared__ __align__(16) float GL[16 * 132];
  __shared__ float hnL[DVV];
  __shared__ float msL[16];

  for (int l = tid; l < 1536 * 16; l += 256) {
    int r = l >> 4, c = l & 15;
    wihL[c * 1540 + r] = w_ih[(size_t)r * 256 + 16 * s + c];
  }
  for (int l = tid; l < 16 * 128; l += 256) {
    int c = l >> 7, d4 = (l & 127) * 4;
    *(float4*)&w2L[c * 520 + d4] = *(const float4*)&w_msg[(size_t)(16 * s + c) * 1280 + 512 + d4];
  }
  for (int l = tid; l < 2048; l += 256) {
    int c = l & 15, j = l >> 4;
    GL[c * 132 + j] = Gini[((size_t)b * NN + j) * DEE + 16 * s + c];
  }
  float bi0 = b_ih[tid], bi1 = b_ih[tid + 256];
  float bi2 = b_ih[512 + tid], bi3 = b_ih[768 + tid];
  float bi4 = b_ih[1024 + tid], bi5 = b_ih[1280 + tid];

  const int c_loc = tid >> 4, jg = tid & 15, j0 = jg << 3;

  short8 Pv; float4 A0, A1; float uu;
  float hv0, hv1, ghr0, ghr1, ghz0, ghz1, ghn0, ghn1;
  {
    size_t rE = ((size_t)(b * NN + 0) * DEE + 16 * s + c_loc) * NN + j0;
    Pv = *(const short8*)&eP16[rE];
    size_t rA = (size_t)(b * NN + 0) * NN + j0;
    A0 = *(const float4*)&adj[rA]; A1 = *(const float4*)&adj[rA + 4];
    uu = U[(size_t)(b * NN + 0) * DEE + 16 * s + c_loc];
    size_t rH = (size_t)(b * NN + 0) * DVV;
    hv0 = h[rH + tid]; hv1 = h[rH + tid + 256];
    size_t rG = (size_t)(b * NN + 0) * 1536;
    ghr0 = GH[rG + tid]; ghr1 = GH[rG + tid + 256];
    ghz0 = GH[rG + 512 + tid]; ghz1 = GH[rG + 768 + tid];
    ghn0 = GH[rG + 1024 + tid]; ghn1 = GH[rG + 1280 + tid];
  }

  for (int i = 0; i < NN; ++i) {
    int g = kround * NN + i;
    float* giA = gi + (size_t)(g % 3) * GISLOT + (size_t)b * 1536;
    float* giZ = gi + (size_t)((g + 1) % 3) * GISLOT + (size_t)b * 1536;
    __syncthreads();   // (1)

    // ---- Phase A ----
    float acc;
    {
      const float* gl = &GL[c_loc * 132 + j0];
      float4 g0 = *(const float4*)&gl[0];
      float4 g1 = *(const float4*)&gl[4];
      float m0 = fmaxf(uu + g0.x + bfu((unsigned short)Pv[0]), 0.f);
      float m1 = fmaxf(uu + g0.y + bfu((unsigned short)Pv[1]), 0.f);
      float m2 = fmaxf(uu + g0.z + bfu((unsigned short)Pv[2]), 0.f);
      float m3 = fmaxf(uu + g0.w + bfu((unsigned short)Pv[3]), 0.f);
      float m4 = fmaxf(uu + g1.x + bfu((unsigned short)Pv[4]), 0.f);
      float m5 = fmaxf(uu + g1.y + bfu((unsigned short)Pv[5]), 0.f);
      float m6 = fmaxf(uu + g1.z + bfu((unsigned short)Pv[6]), 0.f);
      float m7 = fmaxf(uu + g1.w + bfu((unsigned short)Pv[7]), 0.f);
      acc = A0.x * m0 + A0.y * m1 + A0.z * m2 + A0.w * m3
          + A1.x * m4 + A1.y * m5 + A1.z * m6 + A1.w * m7;
      if (WRITE_E) {
        size_t rE = ((size_t)(b * NN + i) * DEE + 16 * s + c_loc) * NN + j0;
        short8 mw;
        mw[0] = (short)f2bf(m0); mw[1] = (short)f2bf(m1); mw[2] = (short)f2bf(m2); mw[3] = (short)f2bf(m3);
        mw[4] = (short)f2bf(m4); mw[5] = (short)f2bf(m5); mw[6] = (short)f2bf(m6); mw[7] = (short)f2bf(m7);
        *(short8*)&eP16[rE] = mw;
      }
    }
    {
      int in = (i < NN - 1) ? i + 1 : NN - 1;
      size_t rE = ((size_t)(b * NN + in) * DEE + 16 * s + c_loc) * NN + j0;
      Pv = *(const short8*)&eP16[rE];
      size_t rA = (size_t)(b * NN + in) * NN + j0;
      A0 = *(const float4*)&adj[rA]; A1 = *(const float4*)&adj[rA + 4];
      uu = U[(size_t)(b * NN + in) * DEE + 16 * s + c_loc];
    }
    acc += __shfl_down(acc, 8);
    acc += __shfl_down(acc, 4);
    acc += __shfl_down(acc, 2);
    acc += __shfl_down(acc, 1);
    if (jg == 0) msL[c_loc] = acc;
    __syncthreads();   // (2)

    // ---- Phase B: atomicAdd partials into slot g%3; zero slot (g+1)%3 ----
    {
      float ms[16];
#pragma unroll
      for (int c = 0; c < 16; ++c) ms[c] = msL[c];
#pragma unroll
      for (int u = 0; u < 6; ++u) {
        int r = tid + (u << 8);
        float pa = 0.f;
#pragma unroll
        for (int c = 0; c < 16; ++c) pa += wihL[c * 1540 + r] * ms[c];
        (void)__hip_atomic_fetch_add(&giA[r], pa, __ATOMIC_RELAXED, __HIP_MEMORY_SCOPE_SYSTEM);
      }
      if (tid < 96)
        __hip_atomic_store(&giZ[96 * s + tid], 0.f, __ATOMIC_RELAXED, __HIP_MEMORY_SCOPE_SYSTEM);
    }

    // ---- flag-array barrier (system-scope) ----
    {
      unsigned tgt = (unsigned)(g + 1);
      __syncthreads();   // (3) drains atomics + zero stores
      if (tid < 64) {
        if (tid == 0)
          __hip_atomic_store(&flags[(((b << 4) + s) << 5)], tgt, __ATOMIC_RELAXED,
                             __HIP_MEMORY_SCOPE_SYSTEM);
        unsigned* fp = &flags[(((b << 4) + (tid & 15)) << 5)];
        for (;;) {
          unsigned v = __hip_atomic_load(fp, __ATOMIC_RELAXED, __HIP_MEMORY_SCOPE_SYSTEM);
          if (!__any(v < tgt)) break;
          __builtin_amdgcn_s_sleep(1);
        }
      }
      __syncthreads();   // (4)
    }

    // ---- GRU: 6 sc1 loads of the summed gi + bias ----
    {
      float sr0 = bi0 + __hip_atomic_load(&giA[tid],        __ATOMIC_RELAXED, __HIP_MEMORY_SCOPE_SYSTEM);
      float sr1 = bi1 + __hip_atomic_load(&giA[tid + 256],  __ATOMIC_RELAXED, __HIP_MEMORY_SCOPE_SYSTEM);
      float sz0 = bi2 + __hip_atomic_load(&giA[512 + tid],  __ATOMIC_RELAXED, __HIP_MEMORY_SCOPE_SYSTEM);
      float sz1 = bi3 + __hip_atomic_load(&giA[768 + tid],  __ATOMIC_RELAXED, __HIP_MEMORY_SCOPE_SYSTEM);
      float sn0 = bi4 + __hip_atomic_load(&giA[1024 + tid], __ATOMIC_RELAXED, __HIP_MEMORY_SCOPE_SYSTEM);
      float sn1 = bi5 + __hip_atomic_load(&giA[1280 + tid], __ATOMIC_RELAXED, __HIP_MEMORY_SCOPE_SYSTEM);
      float rg0 = sigmf(sr0 + ghr0), rg1 = sigmf(sr1 + ghr1);
      float z0 = sigmf(sz0 + ghz0),  z1 = sigmf(sz1 + ghz1);
      float nv0 = tanhf_fast(sn0 + rg0 * ghn0);
      float nv1 = tanhf_fast(sn1 + rg1 * ghn1);
      float hn0 = (1.f - z0) * nv0 + z0 * hv0;
      float hn1 = (1.f - z1) * nv1 + z1 * hv1;
      hnL[tid] = hn0; hnL[tid + 256] = hn1;
      size_t rH = (size_t)(b * NN + i) * DVV;
      if ((tid >> 5) == s)         { h[rH + tid] = hn0;       hb[rH + tid] = f2bf(hn0); }
      if (((tid + 256) >> 5) == s) { h[rH + tid + 256] = hn1; hb[rH + tid + 256] = f2bf(hn1); }
    }
    {
      int in = (i < NN - 1) ? i + 1 : NN - 1;
      size_t rH = (size_t)(b * NN + in) * DVV;
      hv0 = h[rH + tid]; hv1 = h[rH + tid + 256];
      size_t rG = (size_t)(b * NN + in) * 1536;
      ghr0 = GH[rG + tid]; ghr1 = GH[rG + tid + 256];
      ghz0 = GH[rG + 512 + tid]; ghz1 = GH[rG + 768 + tid];
      ghn0 = GH[rG + 1024 + tid]; ghn1 = GH[rG + 1280 + tid];
    }
    __syncthreads();   // (5)

    // ---- Phase C ----
    {
      int cw = tid >> 4, dg = tid & 15;
      float acc2 = 0.f;
#pragma unroll
      for (int it = 0; it < 32; ++it) {
        int d = dg + (it << 4);
        acc2 += w2L[cw * 520 + d] * hnL[d];
      }
      acc2 += __shfl_down(acc2, 8);
      acc2 += __shfl_down(acc2, 4);
      acc2 += __shfl_down(acc2, 2);
      acc2 += __shfl_down(acc2, 1);
      if (dg == 0) GL[cw * 132 + i] = acc2;
    }
  }
}

// ---------------- labels ----------------
__global__ __launch_bounds__(128) void k_labels(const float* __restrict__ h, const float* __restrict__ w_ro,
                                                const float* __restrict__ b_ro, float* __restrict__ out) {
  int b = blockIdx.x >> 7, n = blockIdx.x & 127;
  __shared__ __align__(16) float hr[512];
  int tid = threadIdx.x;
  *(float4*)&hr[tid * 4] = *(const float4*)&h[(size_t)((b << 7) + n) * DVV + tid * 4];
  __syncthreads();
  if (tid < NCC) {
    const float* w = w_ro + (size_t)tid * DVV;
    float acc = b_ro[tid];
    for (int d = 0; d < DVV; d += 4) {
      float4 wv = *(const float4*)&w[d];
      acc += wv.x * hr[d] + wv.y * hr[d + 1] + wv.z * hr[d + 2] + wv.w * hr[d + 3];
    }
    out[(size_t)((b << 7) + n) * NCC + tid] = acc;
  }
}

extern "C" void kernel_launch(void* const* d_in, const int* in_sizes, int n_in,
                              void* d_out, int out_size, void* d_ws, size_t ws_size,
                              hipStream_t stream) {
  const float* edge   = (const float*)d_in[0];
  const float* node   = (const float*)d_in[1];
  const float* w_link = (const float*)d_in[6];
  const float* b_link = (const float*)d_in[7];
  const float* w_msg  = (const float*)d_in[8];
  const float* b_msg  = (const float*)d_in[9];
  const float* w_ih   = (const float*)d_in[10];
  const float* w_hh   = (const float*)d_in[11];
  const float* b_ih   = (const float*)d_in[12];
  const float* b_hh   = (const float*)d_in[13];
  const float* w_ro   = (const float*)d_in[14];
  const float* b_ro   = (const float*)d_in[15];
  float* out = (float*)d_out;
  float* ws  = (float*)d_ws;

  unsigned short* eP16 = (unsigned short*)ws;               // 33,554,432 ushorts
  unsigned short* hb   = (unsigned short*)(ws + 21000000);  //   524,288 ushorts
  float* h_buf  = ws + 33554432ull;        //    524,288  (B,N,DV)
  float* GH_buf = h_buf + 524288;          //  1,572,864  (B,N,1536)
  float* U_buf  = GH_buf + 1572864;        //    262,144  (B,N,256)
  float* G_buf  = U_buf + 262144;          //    262,144  (B,N,256)
  float* lE_buf = G_buf + 262144;          //    131,072  (reused: w3b)
  float* av_buf = lE_buf + 131072;         //      2,048  (B,2,N)
  float* gi_buf = av_buf + 2048;           //     36,864  (3 slots x B x 1536)
  unsigned* flags = (unsigned*)(gi_buf + 3 * GISLOT);  // 4096 u32
  unsigned short* w3b = (unsigned short*)lE_buf;
  size_t need_bytes = 36710304ull * 4ull;
  if (ws_size < need_bytes) return;

  // zero gi slots + flags (contiguous) every call
  hipMemsetAsync(gi_buf, 0, (3 * GISLOT + 4096) * sizeof(float), stream);
  k_copy<<<512, 256, 0, stream>>>(node, h_buf, hb);
  k_cvtw<<<256, 256, 0, stream>>>(w_msg, w3b);

  for (int k = 0; k < 3; ++k) {
    k_av<<<1024, 128, 0, stream>>>(h_buf, w_link, av_buf);
    if (k == 0) k_plogit_mfma<1><<<1024, 256, 0, stream>>>(edge, eP16, w3b, w_link, av_buf, b_link, eP16, out);
    else        k_plogit_mfma<0><<<1024, 256, 0, stream>>>(edge, eP16, w3b, w_link, av_buf, b_link, eP16, out);
    k_wh3<<<dim3(128, 8), 256, 0, stream>>>(w_hh, w_msg, b_hh, b_msg, h_buf, GH_buf, U_buf, G_buf);
    if (k < 2) k_scan13<1><<<dim3(SB, NB), 256, 0, stream>>>(eP16, out, GH_buf, U_buf, G_buf, h_buf, hb,
                                                             w_ih, b_ih, w_msg, gi_buf, flags, k);
    else       k_scan13<0><<<dim3(SB, NB), 256, 0, stream>>>(eP16, out, GH_buf, U_buf, G_buf, h_buf, hb,
                                                             w_ih, b_ih, w_msg, gi_buf, flags, k);
  }
  k_labels<<<1024, 128, 0, stream>>>(h_buf, w_ro, b_ro, out + 131072);
}

// Round 14
// 1874.457 us; speedup vs baseline: 2.5568x; 1.0418x over previous
//
#include <hip/hip_runtime.h>
#include <math.h>

// GPNN: B=8 graphs, N=128 nodes, DV=512, DE=256, K=3, C=117.
// R14: R13 with scan prefetch reordering — all step-(i+1) loads (P/adj/U into
// existing regs, h/GH into temps) issue right after the flag store, BEFORE the
// poll, so they overlap poll + gi-loads + GRU instead of stalling at the next
// __syncthreads vmcnt drain. Protocol/ordering otherwise identical to R13.

#define NB 8
#define NN 128
#define DVV 512
#define DEE 256
#define NCC 117
#define SB 16
#define GISLOT 12288   // floats per gi slot (8 batches x 1536)

typedef __attribute__((ext_vector_type(8))) short short8;
typedef __attribute__((ext_vector_type(4))) float f32x4;

__device__ __forceinline__ float sigmf(float x) {
  x = fminf(fmaxf(x, -30.f), 30.f);
  return 1.0f / (1.0f + __expf(-x));
}
__device__ __forceinline__ float tanhf_fast(float x) {
  x = fminf(fmaxf(x, -15.f), 15.f);
  float e = __expf(2.0f * x);
  return (e - 1.0f) / (e + 1.0f);
}
__device__ __forceinline__ unsigned short f2bf(float f) {
  union { float f; unsigned u; } v; v.f = f;
  unsigned u = v.u + 0x7FFFu + ((v.u >> 16) & 1u);
  return (unsigned short)(u >> 16);
}
__device__ __forceinline__ float bfu(unsigned short u) {
  union { unsigned u; float f; } v; v.u = ((unsigned)u) << 16; return v.f;
}

// ---------------- h init (+ hb bf16) ----------------
__global__ __launch_bounds__(256) void k_copy(const float* __restrict__ src, float* __restrict__ dst,
                                              unsigned short* __restrict__ hb) {
  int i = blockIdx.x * 256 + threadIdx.x;
  float4 v = ((const float4*)src)[i];
  ((float4*)dst)[i] = v;
  unsigned long long pk = (unsigned long long)f2bf(v.x) | ((unsigned long long)f2bf(v.y) << 16)
                        | ((unsigned long long)f2bf(v.z) << 32) | ((unsigned long long)f2bf(v.w) << 48);
  *(unsigned long long*)&hb[i * 4] = pk;
}

// ---------------- W3 -> bf16 (once) ----------------
__global__ __launch_bounds__(256) void k_cvtw(const float* __restrict__ w_msg,
                                              unsigned short* __restrict__ w3b) {
  int idx = blockIdx.x * 256 + threadIdx.x;      // 65536
  int r = idx >> 8, c = idx & 255;
  w3b[idx] = f2bf(w_msg[(size_t)r * 1280 + 1024 + c]);
}

// ---------------- ai/aj ----------------
__global__ __launch_bounds__(128) void k_av(const float* __restrict__ h, const float* __restrict__ w_link,
                                            float* __restrict__ av) {
  int b = blockIdx.x >> 7, n = blockIdx.x & 127;
  int lane = threadIdx.x & 63, half = threadIdx.x >> 6;
  const float* hc = h + (size_t)((b << 7) + n) * DVV;
  const float* w = w_link + half * DVV;
  float acc = 0.f;
#pragma unroll
  for (int t = 0; t < 8; ++t) { int d = lane + (t << 6); acc += w[d] * hc[d]; }
#pragma unroll
  for (int off = 32; off; off >>= 1) acc += __shfl_down(acc, off);
  if (lane == 0) av[(b << 8) + half * NN + n] = acc;
}

// ---------------- per-row: adj (fused) + P = W3 @ e_row via bf16 MFMA; e bf16 [c][j] ----------------
template <int FIRST>
__global__ __launch_bounds__(256) void k_plogit_mfma(
    const float* edge, const unsigned short* eP16in, const unsigned short* __restrict__ w3b,
    const float* __restrict__ w_link, const float* __restrict__ av,
    const float* __restrict__ b_link, unsigned short* eP16out, float* __restrict__ adj_out) {
  int b = blockIdx.x >> 7, i = blockIdx.x & 127;
  __shared__ unsigned short eL[128 * 264];       // [j][c], 528B rows (16B-aligned)
  int tid = threadIdx.x;

  if (FIRST) {
    const float* s0 = edge + (size_t)(b * NN + i) * NN * DEE;
    for (int l = tid; l < 4096; l += 256) {
      int j = l >> 5, c0 = (l & 31) * 8;
      float4 v0 = *(const float4*)&s0[(size_t)j * DEE + c0];
      float4 v1 = *(const float4*)&s0[(size_t)j * DEE + c0 + 4];
      unsigned long long p0 = (unsigned long long)f2bf(v0.x) | ((unsigned long long)f2bf(v0.y) << 16)
                            | ((unsigned long long)f2bf(v0.z) << 32) | ((unsigned long long)f2bf(v0.w) << 48);
      unsigned long long p1 = (unsigned long long)f2bf(v1.x) | ((unsigned long long)f2bf(v1.y) << 16)
                            | ((unsigned long long)f2bf(v1.z) << 32) | ((unsigned long long)f2bf(v1.w) << 48);
      *(unsigned long long*)&eL[j * 264 + c0] = p0;
      *(unsigned long long*)&eL[j * 264 + c0 + 4] = p1;
    }
  } else {
    const unsigned short* s0 = eP16in + (size_t)(b * NN + i) * DEE * NN;
#pragma unroll
    for (int t = 0; t < 2; ++t) {
      int blk = tid + t * 256;                   // 512 8x8 blocks
      int c0 = (blk >> 4) * 8, j0 = (blk & 15) * 8;
      short8 rows[8];
#pragma unroll
      for (int cc = 0; cc < 8; ++cc)
        rows[cc] = *(const short8*)&s0[(size_t)(c0 + cc) * NN + j0];
#pragma unroll
      for (int jj = 0; jj < 8; ++jj) {
        short8 o;
#pragma unroll
        for (int cc = 0; cc < 8; ++cc) o[cc] = rows[cc][jj];
        *(short8*)&eL[(j0 + jj) * 264 + c0] = o;
      }
    }
  }
  __syncthreads();

  // logitE per j
  float accLE = 0.f;
  if (tid < NN) {
    const unsigned short* row = &eL[tid * 264];
    for (int c = 0; c < DEE; ++c) accLE += w_link[1024 + c] * bfu(row[c]);
  }

  // MFMA main loop
  const int w = tid >> 6, l = tid & 63;
  const int lm = l & 15, lg = l >> 4;
  f32x4 acc[4][8];
#pragma unroll
  for (int a = 0; a < 4; ++a)
#pragma unroll
    for (int jt = 0; jt < 8; ++jt) acc[a][jt] = (f32x4){0.f, 0.f, 0.f, 0.f};

#pragma unroll
  for (int kk = 0; kk < 8; ++kk) {
    short8 afr[4];
#pragma unroll
    for (int a = 0; a < 4; ++a)
      afr[a] = *(const short8*)&w3b[(size_t)(64 * w + 16 * a + lm) * 256 + 32 * kk + 8 * lg];
#pragma unroll
    for (int jt = 0; jt < 8; ++jt) {
      short8 bfr = *(const short8*)&eL[(16 * jt + lm) * 264 + 32 * kk + 8 * lg];
#pragma unroll
      for (int a = 0; a < 4; ++a)
        acc[a][jt] = __builtin_amdgcn_mfma_f32_16x16x32_bf16(afr[a], bfr, acc[a][jt], 0, 0, 0);
    }
  }

  // epilogue: P bf16 [c][j]
  unsigned short* Pout = eP16out + (size_t)(b * NN + i) * DEE * NN;
#pragma unroll
  for (int a = 0; a < 4; ++a) {
    int rbase = 64 * w + 16 * a + 4 * lg;
#pragma unroll
    for (int jt = 0; jt < 8; ++jt) {
      int j = 16 * jt + lm;
#pragma unroll
      for (int q = 0; q < 4; ++q)
        Pout[(size_t)(rbase + q) * NN + j] = f2bf(acc[a][jt][q]);
    }
  }
  if (tid < NN) {
    float x = av[(b << 8) + NN + i] + av[(b << 8) + tid] + accLE + b_link[0];
    adj_out[((size_t)b * NN + i) * NN + tid] = sigmf(x);
  }
}

// ---------------- merged W@h kernel (R9 scalar, PROVEN) ----------------
__global__ __launch_bounds__(256) void k_wh3(const float* __restrict__ w_hh, const float* __restrict__ w_msg,
                                             const float* __restrict__ b_hh, const float* __restrict__ b_msg,
                                             const float* __restrict__ h, float* __restrict__ GHo,
                                             float* __restrict__ Uo, float* __restrict__ Go) {
  int bx = blockIdx.x, b = blockIdx.y;
  const float* W; const float* bias; float* out; int ldw, R, r0;
  if (bx < 96)       { W = w_hh;        ldw = 512;  R = 1536; bias = b_hh;   out = GHo; r0 = bx * 16; }
  else if (bx < 112) { W = w_msg;       ldw = 1280; R = 256;  bias = b_msg;  out = Uo;  r0 = (bx - 96) * 16; }
  else               { W = w_msg + 512; ldw = 1280; R = 256;  bias = nullptr; out = Go; r0 = (bx - 112) * 16; }
  __shared__ float hT[128][129];
  __shared__ float wT[16][129];
  __shared__ float outT[16][129];
  int tid = threadIdx.x;
  int n = tid & 127, rr = tid >> 7;
  float acc8[8] = {0, 0, 0, 0, 0, 0, 0, 0};
  for (int dc = 0; dc < DVV; dc += 128) {
    if (dc) __syncthreads();
    for (int l = tid * 4; l < 16384; l += 1024) {
      int nn = l >> 7, d = l & 127;
      float4 v = *(const float4*)&h[((size_t)(b << 7) + nn) * DVV + dc + d];
      hT[d + 0][nn] = v.x; hT[d + 1][nn] = v.y; hT[d + 2][nn] = v.z; hT[d + 3][nn] = v.w;
    }
    for (int l = tid; l < 2048; l += 256) {
      int r = l >> 7, d = l & 127;
      wT[r][d] = W[(size_t)(r0 + r) * ldw + dc + d];
    }
    __syncthreads();
    for (int d = 0; d < 128; ++d) {
      float hval = hT[d][n];
#pragma unroll
      for (int r8 = 0; r8 < 8; ++r8) acc8[r8] += wT[rr * 8 + r8][d] * hval;
    }
  }
#pragma unroll
  for (int r8 = 0; r8 < 8; ++r8) {
    int r = rr * 8 + r8;
    outT[r][n] = acc8[r8] + (bias ? bias[r0 + r] : 0.0f);
  }
  __syncthreads();
  int n2 = tid >> 1, q = tid & 1;
  size_t base = ((size_t)(b << 7) + n2) * R + r0 + q * 8;
  float4 o0; o0.x = outT[q * 8 + 0][n2]; o0.y = outT[q * 8 + 1][n2]; o0.z = outT[q * 8 + 2][n2]; o0.w = outT[q * 8 + 3][n2];
  float4 o1; o1.x = outT[q * 8 + 4][n2]; o1.y = outT[q * 8 + 5][n2]; o1.z = outT[q * 8 + 6][n2]; o1.w = outT[q * 8 + 7][n2];
  *(float4*)&out[base] = o0;
  *(float4*)&out[base + 4] = o1;
}

// ---------------- distributed scan: R13 protocol + early prefetch ----------------
template <int WRITE_E>
__global__ __launch_bounds__(256) void k_scan14(
    unsigned short* eP16, const float* __restrict__ adj, const float* __restrict__ GH,
    const float* __restrict__ U, const float* __restrict__ Gini, float* __restrict__ h,
    unsigned short* __restrict__ hb, const float* __restrict__ w_ih,
    const float* __restrict__ b_ih, const float* __restrict__ w_msg,
    float* __restrict__ gi, unsigned* __restrict__ flags, int kround) {
  const int s = blockIdx.x, b = blockIdx.y, tid = threadIdx.x;
  __shared__ float wihL[16 * 1540];
  __shared__ __align__(16) float w2L[16 * 520];
  __shared__ __align__(16) float GL[16 * 132];
  __shared__ float hnL[DVV];
  __shared__ float msL[16];

  for (int l = tid; l < 1536 * 16; l += 256) {
    int r = l >> 4, c = l & 15;
    wihL[c * 1540 + r] = w_ih[(size_t)r * 256 + 16 * s + c];
  }
  for (int l = tid; l < 16 * 128; l += 256) {
    int c = l >> 7, d4 = (l & 127) * 4;
    *(float4*)&w2L[c * 520 + d4] = *(const float4*)&w_msg[(size_t)(16 * s + c) * 1280 + 512 + d4];
  }
  for (int l = tid; l < 2048; l += 256) {
    int c = l & 15, j = l >> 4;
    GL[c * 132 + j] = Gini[((size_t)b * NN + j) * DEE + 16 * s + c];
  }
  float bi0 = b_ih[tid], bi1 = b_ih[tid + 256];
  float bi2 = b_ih[512 + tid], bi3 = b_ih[768 + tid];
  float bi4 = b_ih[1024 + tid], bi5 = b_ih[1280 + tid];

  const int c_loc = tid >> 4, jg = tid & 15, j0 = jg << 3;

  short8 Pv; float4 A0, A1; float uu;
  float hv0, hv1, ghr0, ghr1, ghz0, ghz1, ghn0, ghn1;
  {
    size_t rE = ((size_t)(b * NN + 0) * DEE + 16 * s + c_loc) * NN + j0;
    Pv = *(const short8*)&eP16[rE];
    size_t rA = (size_t)(b * NN + 0) * NN + j0;
    A0 = *(const float4*)&adj[rA]; A1 = *(const float4*)&adj[rA + 4];
    uu = U[(size_t)(b * NN + 0) * DEE + 16 * s + c_loc];
    size_t rH = (size_t)(b * NN + 0) * DVV;
    hv0 = h[rH + tid]; hv1 = h[rH + tid + 256];
    size_t rG = (size_t)(b * NN + 0) * 1536;
    ghr0 = GH[rG + tid]; ghr1 = GH[rG + tid + 256];
    ghz0 = GH[rG + 512 + tid]; ghz1 = GH[rG + 768 + tid];
    ghn0 = GH[rG + 1024 + tid]; ghn1 = GH[rG + 1280 + tid];
  }

  for (int i = 0; i < NN; ++i) {
    int g = kround * NN + i;
    float* giA = gi + (size_t)(g % 3) * GISLOT + (size_t)b * 1536;
    float* giZ = gi + (size_t)((g + 1) % 3) * GISLOT + (size_t)b * 1536;
    __syncthreads();   // (1)

    // ---- Phase A (uses prefetched Pv/A0/A1/uu) ----
    float acc;
    {
      const float* gl = &GL[c_loc * 132 + j0];
      float4 g0 = *(const float4*)&gl[0];
      float4 g1 = *(const float4*)&gl[4];
      float m0 = fmaxf(uu + g0.x + bfu((unsigned short)Pv[0]), 0.f);
      float m1 = fmaxf(uu + g0.y + bfu((unsigned short)Pv[1]), 0.f);
      float m2 = fmaxf(uu + g0.z + bfu((unsigned short)Pv[2]), 0.f);
      float m3 = fmaxf(uu + g0.w + bfu((unsigned short)Pv[3]), 0.f);
      float m4 = fmaxf(uu + g1.x + bfu((unsigned short)Pv[4]), 0.f);
      float m5 = fmaxf(uu + g1.y + bfu((unsigned short)Pv[5]), 0.f);
      float m6 = fmaxf(uu + g1.z + bfu((unsigned short)Pv[6]), 0.f);
      float m7 = fmaxf(uu + g1.w + bfu((unsigned short)Pv[7]), 0.f);
      acc = A0.x * m0 + A0.y * m1 + A0.z * m2 + A0.w * m3
          + A1.x * m4 + A1.y * m5 + A1.z * m6 + A1.w * m7;
      if (WRITE_E) {
        size_t rE = ((size_t)(b * NN + i) * DEE + 16 * s + c_loc) * NN + j0;
        short8 mw;
        mw[0] = (short)f2bf(m0); mw[1] = (short)f2bf(m1); mw[2] = (short)f2bf(m2); mw[3] = (short)f2bf(m3);
        mw[4] = (short)f2bf(m4); mw[5] = (short)f2bf(m5); mw[6] = (short)f2bf(m6); mw[7] = (short)f2bf(m7);
        *(short8*)&eP16[rE] = mw;
      }
    }
    acc += __shfl_down(acc, 8);
    acc += __shfl_down(acc, 4);
    acc += __shfl_down(acc, 2);
    acc += __shfl_down(acc, 1);
    if (jg == 0) msL[c_loc] = acc;
    __syncthreads();   // (2) — no pending global loads: fast

    // ---- Phase B: atomicAdd into slot g%3; zero slot (g+1)%3 ----
    {
      float ms[16];
#pragma unroll
      for (int c = 0; c < 16; ++c) ms[c] = msL[c];
#pragma unroll
      for (int u = 0; u < 6; ++u) {
        int r = tid + (u << 8);
        float pa = 0.f;
#pragma unroll
        for (int c = 0; c < 16; ++c) pa += wihL[c * 1540 + r] * ms[c];
        (void)__hip_atomic_fetch_add(&giA[r], pa, __ATOMIC_RELAXED, __HIP_MEMORY_SCOPE_SYSTEM);
      }
      if (tid < 96)
        __hip_atomic_store(&giZ[96 * s + tid], 0.f, __ATOMIC_RELAXED, __HIP_MEMORY_SCOPE_SYSTEM);
    }

    // ---- barrier: drain atomics -> flag -> PREFETCH(i+1) -> poll ----
    unsigned tgt = (unsigned)(g + 1);
    __syncthreads();   // (3) drains atomics + zero stores
    if (tid == 0)
      __hip_atomic_store(&flags[(((b << 4) + s) << 5)], tgt, __ATOMIC_RELAXED,
                         __HIP_MEMORY_SCOPE_SYSTEM);
    // prefetch for i+1, issued BEFORE the poll so latency hides under
    // poll + gi loads + GRU. Read-before-write safety: these drain at
    // sync(5) below, which precedes our flag(i+1), which precedes any
    // step-(i+1) writer. (Clamped last-iteration values are dead.)
    float t_hv0, t_hv1, t_ghr0, t_ghr1, t_ghz0, t_ghz1, t_ghn0, t_ghn1;
    {
      int in = (i < NN - 1) ? i + 1 : NN - 1;
      size_t rE = ((size_t)(b * NN + in) * DEE + 16 * s + c_loc) * NN + j0;
      Pv = *(const short8*)&eP16[rE];
      size_t rA = (size_t)(b * NN + in) * NN + j0;
      A0 = *(const float4*)&adj[rA]; A1 = *(const float4*)&adj[rA + 4];
      uu = U[(size_t)(b * NN + in) * DEE + 16 * s + c_loc];
      size_t rH = (size_t)(b * NN + in) * DVV;
      t_hv0 = h[rH + tid]; t_hv1 = h[rH + tid + 256];
      size_t rG = (size_t)(b * NN + in) * 1536;
      t_ghr0 = GH[rG + tid]; t_ghr1 = GH[rG + tid + 256];
      t_ghz0 = GH[rG + 512 + tid]; t_ghz1 = GH[rG + 768 + tid];
      t_ghn0 = GH[rG + 1024 + tid]; t_ghn1 = GH[rG + 1280 + tid];
    }
    if (tid < 64) {
      unsigned* fp = &flags[(((b << 4) + (tid & 15)) << 5)];
      for (;;) {
        unsigned v = __hip_atomic_load(fp, __ATOMIC_RELAXED, __HIP_MEMORY_SCOPE_SYSTEM);
        if (!__any(v < tgt)) break;
        __builtin_amdgcn_s_sleep(1);
      }
    }
    __syncthreads();   // (4)

    // ---- GRU: 6 sc1 loads of summed gi + bias (uses OLD hv/gh regs) ----
    {
      float sr0 = bi0 + __hip_atomic_load(&giA[tid],        __ATOMIC_RELAXED, __HIP_MEMORY_SCOPE_SYSTEM);
      float sr1 = bi1 + __hip_atomic_load(&giA[tid + 256],  __ATOMIC_RELAXED, __HIP_MEMORY_SCOPE_SYSTEM);
      float sz0 = bi2 + __hip_atomic_load(&giA[512 + tid],  __ATOMIC_RELAXED, __HIP_MEMORY_SCOPE_SYSTEM);
      float sz1 = bi3 + __hip_atomic_load(&giA[768 + tid],  __ATOMIC_RELAXED, __HIP_MEMORY_SCOPE_SYSTEM);
      float sn0 = bi4 + __hip_atomic_load(&giA[1024 + tid], __ATOMIC_RELAXED, __HIP_MEMORY_SCOPE_SYSTEM);
      float sn1 = bi5 + __hip_atomic_load(&giA[1280 + tid], __ATOMIC_RELAXED, __HIP_MEMORY_SCOPE_SYSTEM);
      float rg0 = sigmf(sr0 + ghr0), rg1 = sigmf(sr1 + ghr1);
      float z0 = sigmf(sz0 + ghz0),  z1 = sigmf(sz1 + ghz1);
      float nv0 = tanhf_fast(sn0 + rg0 * ghn0);
      float nv1 = tanhf_fast(sn1 + rg1 * ghn1);
      float hn0 = (1.f - z0) * nv0 + z0 * hv0;
      float hn1 = (1.f - z1) * nv1 + z1 * hv1;
      hnL[tid] = hn0; hnL[tid + 256] = hn1;
      size_t rH = (size_t)(b * NN + i) * DVV;
      if ((tid >> 5) == s)         { h[rH + tid] = hn0;       hb[rH + tid] = f2bf(hn0); }
      if (((tid + 256) >> 5) == s) { h[rH + tid + 256] = hn1; hb[rH + tid + 256] = f2bf(hn1); }
    }
    // commit prefetched h/GH for next step
    hv0 = t_hv0; hv1 = t_hv1;
    ghr0 = t_ghr0; ghr1 = t_ghr1;
    ghz0 = t_ghz0; ghz1 = t_ghz1;
    ghn0 = t_ghn0; ghn1 = t_ghn1;
    __syncthreads();   // (5)

    // ---- Phase C ----
    {
      int cw = tid >> 4, dg = tid & 15;
      float acc2 = 0.f;
#pragma unroll
      for (int it = 0; it < 32; ++it) {
        int d = dg + (it << 4);
        acc2 += w2L[cw * 520 + d] * hnL[d];
      }
      acc2 += __shfl_down(acc2, 8);
      acc2 += __shfl_down(acc2, 4);
      acc2 += __shfl_down(acc2, 2);
      acc2 += __shfl_down(acc2, 1);
      if (dg == 0) GL[cw * 132 + i] = acc2;
    }
  }
}

// ---------------- labels ----------------
__global__ __launch_bounds__(128) void k_labels(const float* __restrict__ h, const float* __restrict__ w_ro,
                                                const float* __restrict__ b_ro, float* __restrict__ out) {
  int b = blockIdx.x >> 7, n = blockIdx.x & 127;
  __shared__ __align__(16) float hr[512];
  int tid = threadIdx.x;
  *(float4*)&hr[tid * 4] = *(const float4*)&h[(size_t)((b << 7) + n) * DVV + tid * 4];
  __syncthreads();
  if (tid < NCC) {
    const float* w = w_ro + (size_t)tid * DVV;
    float acc = b_ro[tid];
    for (int d = 0; d < DVV; d += 4) {
      float4 wv = *(const float4*)&w[d];
      acc += wv.x * hr[d] + wv.y * hr[d + 1] + wv.z * hr[d + 2] + wv.w * hr[d + 3];
    }
    out[(size_t)((b << 7) + n) * NCC + tid] = acc;
  }
}

extern "C" void kernel_launch(void* const* d_in, const int* in_sizes, int n_in,
                              void* d_out, int out_size, void* d_ws, size_t ws_size,
                              hipStream_t stream) {
  const float* edge   = (const float*)d_in[0];
  const float* node   = (const float*)d_in[1];
  const float* w_link = (const float*)d_in[6];
  const float* b_link = (const float*)d_in[7];
  const float* w_msg  = (const float*)d_in[8];
  const float* b_msg  = (const float*)d_in[9];
  const float* w_ih   = (const float*)d_in[10];
  const float* w_hh   = (const float*)d_in[11];
  const float* b_ih   = (const float*)d_in[12];
  const float* b_hh   = (const float*)d_in[13];
  const float* w_ro   = (const float*)d_in[14];
  const float* b_ro   = (const float*)d_in[15];
  float* out = (float*)d_out;
  float* ws  = (float*)d_ws;

  unsigned short* eP16 = (unsigned short*)ws;               // 33,554,432 ushorts
  unsigned short* hb   = (unsigned short*)(ws + 21000000);  //   524,288 ushorts
  float* h_buf  = ws + 33554432ull;        //    524,288  (B,N,DV)
  float* GH_buf = h_buf + 524288;          //  1,572,864  (B,N,1536)
  float* U_buf  = GH_buf + 1572864;        //    262,144  (B,N,256)
  float* G_buf  = U_buf + 262144;          //    262,144  (B,N,256)
  float* lE_buf = G_buf + 262144;          //    131,072  (reused: w3b)
  float* av_buf = lE_buf + 131072;         //      2,048  (B,2,N)
  float* gi_buf = av_buf + 2048;           //     36,864  (3 slots x B x 1536)
  unsigned* flags = (unsigned*)(gi_buf + 3 * GISLOT);  // 4096 u32
  unsigned short* w3b = (unsigned short*)lE_buf;
  size_t need_bytes = 36710304ull * 4ull;
  if (ws_size < need_bytes) return;

  hipMemsetAsync(gi_buf, 0, (3 * GISLOT + 4096) * sizeof(float), stream);
  k_copy<<<512, 256, 0, stream>>>(node, h_buf, hb);
  k_cvtw<<<256, 256, 0, stream>>>(w_msg, w3b);

  for (int k = 0; k < 3; ++k) {
    k_av<<<1024, 128, 0, stream>>>(h_buf, w_link, av_buf);
    if (k == 0) k_plogit_mfma<1><<<1024, 256, 0, stream>>>(edge, eP16, w3b, w_link, av_buf, b_link, eP16, out);
    else        k_plogit_mfma<0><<<1024, 256, 0, stream>>>(edge, eP16, w3b, w_link, av_buf, b_link, eP16, out);
    k_wh3<<<dim3(128, 8), 256, 0, stream>>>(w_hh, w_msg, b_hh, b_msg, h_buf, GH_buf, U_buf, G_buf);
    if (k < 2) k_scan14<1><<<dim3(SB, NB), 256, 0, stream>>>(eP16, out, GH_buf, U_buf, G_buf, h_buf, hb,
                                                             w_ih, b_ih, w_msg, gi_buf, flags, k);
    else       k_scan14<0><<<dim3(SB, NB), 256, 0, stream>>>(eP16, out, GH_buf, U_buf, G_buf, h_buf, hb,
                                                             w_ih, b_ih, w_msg, gi_buf, flags, k);
  }
  k_labels<<<1024, 128, 0, stream>>>(h_buf, w_ro, b_ro, out + 131072);
}